// Round 1
// baseline (3613.408 us; speedup 1.0000x reference)
//
#include <hip/hip_runtime.h>
#include <hip/hip_bf16.h>

typedef __hip_bfloat16 bf16;
typedef __hip_bfloat162 bf162;

// B=4, T=12, P=196, D=512, H=8, DH=64
// M_ROWS = B*T*P = 9408
#define EPS 1e-6f

__device__ __forceinline__ float gelu_exact(float v) {
  return 0.5f * v * (1.0f + erff(v * 0.7071067811865475f));
}

struct alignas(16) bf16x8 { bf16 v[8]; };
struct alignas(8)  bf16x4 { bf16 v[4]; };

// ---------------- LayerNorm f32 -> f32, one 64-thread block per row of 512 --
__global__ __launch_bounds__(64) void norm_f32_kernel(
    const float* __restrict__ in, float* __restrict__ out,
    const float* __restrict__ alpha, const float* __restrict__ beta)
{
  size_t row = blockIdx.x;
  int l = threadIdx.x;
  const float* r = in + row * 512 + l * 8;
  float4 v0 = *(const float4*)(r);
  float4 v1 = *(const float4*)(r + 4);
  float f[8] = {v0.x, v0.y, v0.z, v0.w, v1.x, v1.y, v1.z, v1.w};
  float s = 0.f, ss = 0.f;
#pragma unroll
  for (int q = 0; q < 8; ++q) { s += f[q]; ss += f[q] * f[q]; }
#pragma unroll
  for (int off = 32; off; off >>= 1) { s += __shfl_xor(s, off); ss += __shfl_xor(ss, off); }
  float mu = s * (1.f / 512.f);
  float var = fmaxf((ss - 512.f * mu * mu) * (1.f / 511.f), 0.f);
  float inv = 1.f / (sqrtf(var) + EPS);
  const float* al = alpha + l * 8;
  const float* be = beta + l * 8;
  float4 a0 = *(const float4*)al, a1 = *(const float4*)(al + 4);
  float4 b0 = *(const float4*)be, b1 = *(const float4*)(be + 4);
  float aa[8] = {a0.x, a0.y, a0.z, a0.w, a1.x, a1.y, a1.z, a1.w};
  float bb[8] = {b0.x, b0.y, b0.z, b0.w, b1.x, b1.y, b1.z, b1.w};
  float o[8];
#pragma unroll
  for (int q = 0; q < 8; ++q) o[q] = aa[q] * (f[q] - mu) * inv + bb[q];
  float* wo = out + row * 512 + l * 8;
  *(float4*)(wo)     = make_float4(o[0], o[1], o[2], o[3]);
  *(float4*)(wo + 4) = make_float4(o[4], o[5], o[6], o[7]);
}

// ------------- LayerNorm bf16 in-place + pos add (x2p = norm(av)+pos) -------
__global__ __launch_bounds__(64) void norm_av_kernel(
    bf16* __restrict__ av, const float* __restrict__ alpha,
    const float* __restrict__ beta, const float* __restrict__ pos)
{
  size_t row = blockIdx.x;          // [0, B*T*T*P)
  int l = threadIdx.x;
  bf16* r = av + row * 512 + (size_t)l * 8;
  bf16x8 ib = *(const bf16x8*)r;
  float f[8];
#pragma unroll
  for (int q = 0; q < 8; ++q) f[q] = __bfloat162float(ib.v[q]);
  float s = 0.f, ss = 0.f;
#pragma unroll
  for (int q = 0; q < 8; ++q) { s += f[q]; ss += f[q] * f[q]; }
#pragma unroll
  for (int off = 32; off; off >>= 1) { s += __shfl_xor(s, off); ss += __shfl_xor(ss, off); }
  float mu = s * (1.f / 512.f);
  float var = fmaxf((ss - 512.f * mu * mu) * (1.f / 511.f), 0.f);
  float inv = 1.f / (sqrtf(var) + EPS);
  size_t prow = row % 28224;        // T*T*P  (pos broadcasts over batch)
  const float* pr = pos + prow * 512 + l * 8;
  float4 p0 = *(const float4*)pr, p1 = *(const float4*)(pr + 4);
  const float* al = alpha + l * 8;
  const float* be = beta + l * 8;
  float4 a0 = *(const float4*)al, a1 = *(const float4*)(al + 4);
  float4 b0 = *(const float4*)be, b1 = *(const float4*)(be + 4);
  float pa[8] = {p0.x, p0.y, p0.z, p0.w, p1.x, p1.y, p1.z, p1.w};
  float aa[8] = {a0.x, a0.y, a0.z, a0.w, a1.x, a1.y, a1.z, a1.w};
  float bb[8] = {b0.x, b0.y, b0.z, b0.w, b1.x, b1.y, b1.z, b1.w};
  bf16x8 ob;
#pragma unroll
  for (int q = 0; q < 8; ++q)
    ob.v[q] = __float2bfloat16(aa[q] * (f[q] - mu) * inv + bb[q] + pa[q]);
  *(bf16x8*)r = ob;
}

// ------------- generic NT GEMM: C = epi(A[M,K] @ B[N,K]^T + bias) ----------
// epi: 0 = bias only, 1 = gelu(.+bias), 2 = res + gelu(.+bias)
__global__ __launch_bounds__(256) void gemm_nt_kernel(
    const float* __restrict__ A, const float* __restrict__ B,
    const float* __restrict__ bias, float* __restrict__ C,
    const float* __restrict__ res, int M, int N, int K, int epi)
{
  __shared__ float As[64][20];
  __shared__ float Bs[64][20];
  int n0 = blockIdx.x * 64, m0 = blockIdx.y * 64;
  int tid = threadIdx.x;
  int tx = tid & 15, ty = tid >> 4;
  int lr = tid >> 2, lc = (tid & 3) * 4;
  const float* ap = A + (size_t)(m0 + lr) * K + lc;
  const float* bp = B + (size_t)(n0 + lr) * K + lc;
  float acc[4][4] = {};
  for (int k0 = 0; k0 < K; k0 += 16) {
    float4 a4 = *(const float4*)(ap + k0);
    float4 b4 = *(const float4*)(bp + k0);
    __syncthreads();
    *(float4*)&As[lr][lc] = a4;
    *(float4*)&Bs[lr][lc] = b4;
    __syncthreads();
#pragma unroll
    for (int kk = 0; kk < 16; ++kk) {
      float av_[4], bv_[4];
#pragma unroll
      for (int i = 0; i < 4; ++i) av_[i] = As[ty + 16 * i][kk];
#pragma unroll
      for (int j = 0; j < 4; ++j) bv_[j] = Bs[tx + 16 * j][kk];
#pragma unroll
      for (int i = 0; i < 4; ++i)
#pragma unroll
        for (int j = 0; j < 4; ++j)
          acc[i][j] += av_[i] * bv_[j];
    }
  }
#pragma unroll
  for (int j = 0; j < 4; ++j) {
    int n = n0 + tx + 16 * j;
    float bj = bias[n];
#pragma unroll
    for (int i = 0; i < 4; ++i) {
      int m = m0 + ty + 16 * i;
      float v = acc[i][j] + bj;
      if (epi >= 1) v = gelu_exact(v);
      if (epi == 2) v += res[(size_t)m * N + n];
      C[(size_t)m * N + n] = v;
    }
  }
}

// ------- temporal mixing: xmid = x + gelu( sum_u x2p[b,t,u]@Wt[u]^T /12 + sum_u bt[u] )
__global__ __launch_bounds__(256) void gemm_tc_kernel(
    const bf16* __restrict__ X2p, const float* __restrict__ Wt,
    const float* __restrict__ bt, const float* __restrict__ xin,
    float* __restrict__ xmid)
{
  __shared__ float As[64][20];
  __shared__ float Bs[64][20];
  int n0 = blockIdx.x * 64, m0 = blockIdx.y * 64;
  int tid = threadIdx.x;
  int tx = tid & 15, ty = tid >> 4;
  int lr = tid >> 2, lc = (tid & 3) * 4;
  int mrow = m0 + lr;
  int btq = mrow / 196;             // (b*T+t)
  int p = mrow - btq * 196;
  size_t abase = (size_t)btq * (12 * 196 * 512) + (size_t)p * 512 + lc;
  float acc[4][4] = {};
  for (int u = 0; u < 12; ++u) {
    const bf16* Au = X2p + abase + (size_t)u * (196 * 512);
    const float* Bu = Wt + (size_t)u * (512 * 512) + (size_t)(n0 + lr) * 512 + lc;
    for (int k0 = 0; k0 < 512; k0 += 16) {
      bf16x4 a4 = *(const bf16x4*)(Au + k0);
      float4 b4 = *(const float4*)(Bu + k0);
      __syncthreads();
      As[lr][lc + 0] = __bfloat162float(a4.v[0]);
      As[lr][lc + 1] = __bfloat162float(a4.v[1]);
      As[lr][lc + 2] = __bfloat162float(a4.v[2]);
      As[lr][lc + 3] = __bfloat162float(a4.v[3]);
      *(float4*)&Bs[lr][lc] = b4;
      __syncthreads();
#pragma unroll
      for (int kk = 0; kk < 16; ++kk) {
        float av_[4], bv_[4];
#pragma unroll
        for (int i = 0; i < 4; ++i) av_[i] = As[ty + 16 * i][kk];
#pragma unroll
        for (int j = 0; j < 4; ++j) bv_[j] = Bs[tx + 16 * j][kk];
#pragma unroll
        for (int i = 0; i < 4; ++i)
#pragma unroll
          for (int j = 0; j < 4; ++j)
            acc[i][j] += av_[i] * bv_[j];
      }
    }
  }
#pragma unroll
  for (int j = 0; j < 4; ++j) {
    int n = n0 + tx + 16 * j;
    float sbt = 0.f;
#pragma unroll
    for (int uu = 0; uu < 12; ++uu) sbt += bt[uu * 512 + n];
#pragma unroll
    for (int i = 0; i < 4; ++i) {
      int m = m0 + ty + 16 * i;
      float v = acc[i][j] * (1.f / 12.f) + sbt;
      xmid[(size_t)m * 512 + n] = xin[(size_t)m * 512 + n] + gelu_exact(v);
    }
  }
}

// ------------- attention: one block per (b,t,u,h) ---------------------------
// Q,K,V in [ (b,t,p), h*64+dh ] layout (plain GEMM output). av out bf16
// [B,T,T,P,D]. LDS: K bf16 [196][66], V^T bf16 [64][198], P 8x196 f32 = 57.5KB
__global__ __launch_bounds__(512) void attn_kernel(
    const float* __restrict__ Q, const float* __restrict__ K,
    const float* __restrict__ V, bf16* __restrict__ av)
{
  __shared__ bf16 Ks[196 * 66];
  __shared__ bf16 Vt[64 * 198];
  __shared__ float Ps[8 * 196];

  int blk = blockIdx.x;
  int h = blk & 7;
  int r0 = blk >> 3;
  int u = r0 % 12; r0 /= 12;
  int t = r0 % 12;
  int b = r0 / 12;

  const float* Kp = K + ((size_t)(b * 12 + u) * 196) * 512 + h * 64;
  const float* Vp = V + ((size_t)(b * 12 + u) * 196) * 512 + h * 64;
  const float* Qp = Q + ((size_t)(b * 12 + t) * 196) * 512 + h * 64;
  bf16* avp = av + ((size_t)((b * 12 + t) * 12 + u) * 196) * 512 + h * 64;

  for (int idx = threadIdx.x; idx < 196 * 64; idx += 512) {
    int r = idx >> 6, c = idx & 63;
    float kv = Kp[(size_t)r * 512 + c];
    float vv = Vp[(size_t)r * 512 + c];
    Ks[r * 66 + c] = __float2bfloat16(kv);
    Vt[c * 198 + r] = __float2bfloat16(vv);
  }
  __syncthreads();

  int w = threadIdx.x >> 6, l = threadIdx.x & 63;
  float* prow = &Ps[w * 196];

  for (int i = w; i < 196; i += 8) {
    float q = Qp[(size_t)i * 512 + l];
    int j3 = (l < 4) ? (l + 192) : 0;
    const bf162* k0p = (const bf162*)&Ks[(l      ) * 66];
    const bf162* k1p = (const bf162*)&Ks[(l +  64) * 66];
    const bf162* k2p = (const bf162*)&Ks[(l + 128) * 66];
    const bf162* k3p = (const bf162*)&Ks[(j3     ) * 66];
    float a0 = 0.f, a1 = 0.f, a2 = 0.f, a3 = 0.f;
#pragma unroll
    for (int w2 = 0; w2 < 32; ++w2) {
      float q0 = __shfl(q, 2 * w2);
      float q1 = __shfl(q, 2 * w2 + 1);
      float2 kf0 = __bfloat1622float2(k0p[w2]);
      float2 kf1 = __bfloat1622float2(k1p[w2]);
      float2 kf2 = __bfloat1622float2(k2p[w2]);
      float2 kf3 = __bfloat1622float2(k3p[w2]);
      a0 += q0 * kf0.x + q1 * kf0.y;
      a1 += q0 * kf1.x + q1 * kf1.y;
      a2 += q0 * kf2.x + q1 * kf2.y;
      a3 += q0 * kf3.x + q1 * kf3.y;
    }
    float s0 = a0 * 0.125f, s1 = a1 * 0.125f, s2 = a2 * 0.125f;
    float s3 = (l < 4) ? (a3 * 0.125f) : -3.0e38f;
    float mx = fmaxf(fmaxf(s0, s1), fmaxf(s2, s3));
#pragma unroll
    for (int off = 32; off; off >>= 1) mx = fmaxf(mx, __shfl_xor(mx, off));
    float e0 = expf(s0 - mx), e1 = expf(s1 - mx), e2 = expf(s2 - mx);
    float e3 = (l < 4) ? expf(s3 - mx) : 0.f;
    float sum = e0 + e1 + e2 + e3;
#pragma unroll
    for (int off = 32; off; off >>= 1) sum += __shfl_xor(sum, off);
    prow[l] = e0; prow[l + 64] = e1; prow[l + 128] = e2;
    if (l < 4) prow[l + 192] = e3;
    __threadfence_block();   // per-wave LDS write->read ordering
    const bf162* vrow = (const bf162*)&Vt[l * 198];
    const float2* pp = (const float2*)prow;
    float acc = 0.f;
#pragma unroll 4
    for (int m2 = 0; m2 < 98; ++m2) {
      float2 pv = pp[m2];
      float2 vf = __bfloat1622float2(vrow[m2]);
      acc += pv.x * vf.x + pv.y * vf.y;
    }
    avp[(size_t)i * 512 + l] = __float2bfloat16(acc / sum);
  }
}

extern "C" void kernel_launch(void* const* d_in, const int* in_sizes, int n_in,
                              void* d_out, int out_size, void* d_ws, size_t ws_size,
                              hipStream_t stream)
{
  const float* x      = (const float*)d_in[0];
  const float* Wq     = (const float*)d_in[1];
  const float* bq     = (const float*)d_in[2];
  const float* Wk     = (const float*)d_in[3];
  const float* bk     = (const float*)d_in[4];
  const float* Wv     = (const float*)d_in[5];
  const float* bv     = (const float*)d_in[6];
  const float* in_a   = (const float*)d_in[7];
  const float* in_b   = (const float*)d_in[8];
  const float* attn_a = (const float*)d_in[9];
  const float* attn_b = (const float*)d_in[10];
  const float* out_a  = (const float*)d_in[11];
  const float* out_b  = (const float*)d_in[12];
  const float* Wt     = (const float*)d_in[13];
  const float* bt     = (const float*)d_in[14];
  const float* pos    = (const float*)d_in[15];
  const float* W1     = (const float*)d_in[16];
  const float* b1     = (const float*)d_in[17];
  const float* W2     = (const float*)d_in[18];
  const float* b2     = (const float*)d_in[19];

  char* ws = (char*)d_ws;
  const size_t MD = (size_t)9408 * 512;        // 4,816,896 elems
  const size_t fbytes = MD * 4;                // 19,267,584 B
  float* x2   = (float*)(ws);                  // normed input; later reused as x3
  float* Qb   = (float*)(ws + fbytes);         // later reused (with Kb) as h
  float* Kb   = (float*)(ws + 2 * fbytes);
  float* Vb   = (float*)(ws + 3 * fbytes);     // later reused as xmid
  bf16*  av   = (bf16*)(ws + 4 * fbytes);      // B*T*T*P*D bf16 = 115.6 MB
  float* xmid = Vb;
  float* x3   = x2;
  float* hbuf = Qb;                            // 9408 x 1024 f32 over Q+K
  float* out  = (float*)d_out;

  dim3 g8(8, 147), g16(16, 147);

  // 1. x2 = norm(x, in_a, in_b)
  norm_f32_kernel<<<9408, 64, 0, stream>>>(x, x2, in_a, in_b);
  // 2. Q/K/V = x2 @ W^T + b   (layout [(b,t,p), h*64+dh])
  gemm_nt_kernel<<<g8, 256, 0, stream>>>(x2, Wq, bq, Qb, nullptr, 9408, 512, 512, 0);
  gemm_nt_kernel<<<g8, 256, 0, stream>>>(x2, Wk, bk, Kb, nullptr, 9408, 512, 512, 0);
  gemm_nt_kernel<<<g8, 256, 0, stream>>>(x2, Wv, bv, Vb, nullptr, 9408, 512, 512, 0);
  // 3. av[b,t,u,p,:] = softmax(QK^T/8) V   per (b,t,u,h)
  attn_kernel<<<4608, 512, 0, stream>>>(Qb, Kb, Vb, av);
  // 4. x2p = norm(av, attn_a, attn_b) + pos   (in place, bf16)
  norm_av_kernel<<<112896, 64, 0, stream>>>(av, attn_a, attn_b, pos);
  // 5. xmid = x + gelu( sum_u x2p_u @ Wt[u]^T /12 + sum_u bt[u] )
  gemm_tc_kernel<<<g8, 256, 0, stream>>>(av, Wt, bt, x, xmid);
  // 6. x3 = norm(xmid, out_a, out_b)
  norm_f32_kernel<<<9408, 64, 0, stream>>>(xmid, x3, out_a, out_b);
  // 7. h = gelu(x3 @ W1^T + b1)
  gemm_nt_kernel<<<g16, 256, 0, stream>>>(x3, W1, b1, hbuf, nullptr, 9408, 1024, 512, 1);
  // 8. out = xmid + gelu(h @ W2^T + b2)
  gemm_nt_kernel<<<g8, 256, 0, stream>>>(hbuf, W2, b2, out, xmid, 9408, 512, 1024, 2);
}

// Round 2
// 1969.236 us; speedup vs baseline: 1.8349x; 1.8349x over previous
//
#include <hip/hip_runtime.h>
#include <hip/hip_bf16.h>

typedef __hip_bfloat16 bf16;
typedef __hip_bfloat162 bf162;

typedef __bf16 bfrag8 __attribute__((ext_vector_type(8)));
typedef float  ffrag4 __attribute__((ext_vector_type(4)));

// B=4, T=12, P=196, D=512, H=8, DH=64
#define EPS 1e-6f

__device__ __forceinline__ float gelu_exact(float v) {
  return 0.5f * v * (1.0f + erff(v * 0.7071067811865475f));
}

struct alignas(16) bf16x8 { bf16 v[8]; };
struct alignas(8)  bf16x4 { bf16 v[4]; };

// ---------------- LayerNorm f32 -> f32, one 64-thread block per row of 512 --
__global__ __launch_bounds__(64) void norm_f32_kernel(
    const float* __restrict__ in, float* __restrict__ out,
    const float* __restrict__ alpha, const float* __restrict__ beta)
{
  size_t row = blockIdx.x;
  int l = threadIdx.x;
  const float* r = in + row * 512 + l * 8;
  float4 v0 = *(const float4*)(r);
  float4 v1 = *(const float4*)(r + 4);
  float f[8] = {v0.x, v0.y, v0.z, v0.w, v1.x, v1.y, v1.z, v1.w};
  float s = 0.f, ss = 0.f;
#pragma unroll
  for (int q = 0; q < 8; ++q) { s += f[q]; ss += f[q] * f[q]; }
#pragma unroll
  for (int off = 32; off; off >>= 1) { s += __shfl_xor(s, off); ss += __shfl_xor(ss, off); }
  float mu = s * (1.f / 512.f);
  float var = fmaxf((ss - 512.f * mu * mu) * (1.f / 511.f), 0.f);
  float inv = 1.f / (sqrtf(var) + EPS);
  const float* al = alpha + l * 8;
  const float* be = beta + l * 8;
  float4 a0 = *(const float4*)al, a1 = *(const float4*)(al + 4);
  float4 b0 = *(const float4*)be, b1 = *(const float4*)(be + 4);
  float aa[8] = {a0.x, a0.y, a0.z, a0.w, a1.x, a1.y, a1.z, a1.w};
  float bb[8] = {b0.x, b0.y, b0.z, b0.w, b1.x, b1.y, b1.z, b1.w};
  float o[8];
#pragma unroll
  for (int q = 0; q < 8; ++q) o[q] = aa[q] * (f[q] - mu) * inv + bb[q];
  float* wo = out + row * 512 + l * 8;
  *(float4*)(wo)     = make_float4(o[0], o[1], o[2], o[3]);
  *(float4*)(wo + 4) = make_float4(o[4], o[5], o[6], o[7]);
}

// ------------- LayerNorm bf16 in-place + pos add (x2p = norm(av)+pos) -------
__global__ __launch_bounds__(64) void norm_av_kernel(
    bf16* __restrict__ av, const float* __restrict__ alpha,
    const float* __restrict__ beta, const float* __restrict__ pos)
{
  size_t row = blockIdx.x;          // [0, B*T*T*P)
  int l = threadIdx.x;
  bf16* r = av + row * 512 + (size_t)l * 8;
  bf16x8 ib = *(const bf16x8*)r;
  float f[8];
#pragma unroll
  for (int q = 0; q < 8; ++q) f[q] = __bfloat162float(ib.v[q]);
  float s = 0.f, ss = 0.f;
#pragma unroll
  for (int q = 0; q < 8; ++q) { s += f[q]; ss += f[q] * f[q]; }
#pragma unroll
  for (int off = 32; off; off >>= 1) { s += __shfl_xor(s, off); ss += __shfl_xor(ss, off); }
  float mu = s * (1.f / 512.f);
  float var = fmaxf((ss - 512.f * mu * mu) * (1.f / 511.f), 0.f);
  float inv = 1.f / (sqrtf(var) + EPS);
  size_t prow = row % 28224;        // T*T*P  (pos broadcasts over batch)
  const float* pr = pos + prow * 512 + l * 8;
  float4 p0 = *(const float4*)pr, p1 = *(const float4*)(pr + 4);
  const float* al = alpha + l * 8;
  const float* be = beta + l * 8;
  float4 a0 = *(const float4*)al, a1 = *(const float4*)(al + 4);
  float4 b0 = *(const float4*)be, b1 = *(const float4*)(be + 4);
  float pa[8] = {p0.x, p0.y, p0.z, p0.w, p1.x, p1.y, p1.z, p1.w};
  float aa[8] = {a0.x, a0.y, a0.z, a0.w, a1.x, a1.y, a1.z, a1.w};
  float bb[8] = {b0.x, b0.y, b0.z, b0.w, b1.x, b1.y, b1.z, b1.w};
  bf16x8 ob;
#pragma unroll
  for (int q = 0; q < 8; ++q)
    ob.v[q] = __float2bfloat16(aa[q] * (f[q] - mu) * inv + bb[q] + pa[q]);
  *(bf16x8*)r = ob;
}

// ------------- generic NT GEMM: C = epi(A[M,K] @ B[N,K]^T + bias) ----------
// epi: 0 = bias only, 1 = gelu(.+bias), 2 = res + gelu(.+bias)
__global__ __launch_bounds__(256) void gemm_nt_kernel(
    const float* __restrict__ A, const float* __restrict__ B,
    const float* __restrict__ bias, float* __restrict__ C,
    const float* __restrict__ res, int M, int N, int K, int epi)
{
  __shared__ float As[64][20];
  __shared__ float Bs[64][20];
  int n0 = blockIdx.x * 64, m0 = blockIdx.y * 64;
  int tid = threadIdx.x;
  int tx = tid & 15, ty = tid >> 4;
  int lr = tid >> 2, lc = (tid & 3) * 4;
  const float* ap = A + (size_t)(m0 + lr) * K + lc;
  const float* bp = B + (size_t)(n0 + lr) * K + lc;
  float acc[4][4] = {};
  for (int k0 = 0; k0 < K; k0 += 16) {
    float4 a4 = *(const float4*)(ap + k0);
    float4 b4 = *(const float4*)(bp + k0);
    __syncthreads();
    *(float4*)&As[lr][lc] = a4;
    *(float4*)&Bs[lr][lc] = b4;
    __syncthreads();
#pragma unroll
    for (int kk = 0; kk < 16; ++kk) {
      float av_[4], bv_[4];
#pragma unroll
      for (int i = 0; i < 4; ++i) av_[i] = As[ty + 16 * i][kk];
#pragma unroll
      for (int j = 0; j < 4; ++j) bv_[j] = Bs[tx + 16 * j][kk];
#pragma unroll
      for (int i = 0; i < 4; ++i)
#pragma unroll
        for (int j = 0; j < 4; ++j)
          acc[i][j] += av_[i] * bv_[j];
    }
  }
#pragma unroll
  for (int j = 0; j < 4; ++j) {
    int n = n0 + tx + 16 * j;
    float bj = bias[n];
#pragma unroll
    for (int i = 0; i < 4; ++i) {
      int m = m0 + ty + 16 * i;
      float v = acc[i][j] + bj;
      if (epi >= 1) v = gelu_exact(v);
      if (epi == 2) v += res[(size_t)m * N + n];
      C[(size_t)m * N + n] = v;
    }
  }
}

// ------- temporal mixing: xmid = x + gelu( sum_u x2p[b,t,u]@Wt[u]^T /12 + sum_u bt[u] )
__global__ __launch_bounds__(256) void gemm_tc_kernel(
    const bf16* __restrict__ X2p, const float* __restrict__ Wt,
    const float* __restrict__ bt, const float* __restrict__ xin,
    float* __restrict__ xmid)
{
  __shared__ float As[64][20];
  __shared__ float Bs[64][20];
  int n0 = blockIdx.x * 64, m0 = blockIdx.y * 64;
  int tid = threadIdx.x;
  int tx = tid & 15, ty = tid >> 4;
  int lr = tid >> 2, lc = (tid & 3) * 4;
  int mrow = m0 + lr;
  int btq = mrow / 196;             // (b*T+t)
  int p = mrow - btq * 196;
  size_t abase = (size_t)btq * (12 * 196 * 512) + (size_t)p * 512 + lc;
  float acc[4][4] = {};
  for (int u = 0; u < 12; ++u) {
    const bf16* Au = X2p + abase + (size_t)u * (196 * 512);
    const float* Bu = Wt + (size_t)u * (512 * 512) + (size_t)(n0 + lr) * 512 + lc;
    for (int k0 = 0; k0 < 512; k0 += 16) {
      bf16x4 a4 = *(const bf16x4*)(Au + k0);
      float4 b4 = *(const float4*)(Bu + k0);
      __syncthreads();
      As[lr][lc + 0] = __bfloat162float(a4.v[0]);
      As[lr][lc + 1] = __bfloat162float(a4.v[1]);
      As[lr][lc + 2] = __bfloat162float(a4.v[2]);
      As[lr][lc + 3] = __bfloat162float(a4.v[3]);
      *(float4*)&Bs[lr][lc] = b4;
      __syncthreads();
#pragma unroll
      for (int kk = 0; kk < 16; ++kk) {
        float av_[4], bv_[4];
#pragma unroll
        for (int i = 0; i < 4; ++i) av_[i] = As[ty + 16 * i][kk];
#pragma unroll
        for (int j = 0; j < 4; ++j) bv_[j] = Bs[tx + 16 * j][kk];
#pragma unroll
        for (int i = 0; i < 4; ++i)
#pragma unroll
          for (int j = 0; j < 4; ++j)
            acc[i][j] += av_[i] * bv_[j];
      }
    }
  }
#pragma unroll
  for (int j = 0; j < 4; ++j) {
    int n = n0 + tx + 16 * j;
    float sbt = 0.f;
#pragma unroll
    for (int uu = 0; uu < 12; ++uu) sbt += bt[uu * 512 + n];
#pragma unroll
    for (int i = 0; i < 4; ++i) {
      int m = m0 + ty + 16 * i;
      float v = acc[i][j] * (1.f / 12.f) + sbt;
      xmid[(size_t)m * 512 + n] = xin[(size_t)m * 512 + n] + gelu_exact(v);
    }
  }
}

// ------------- MFMA attention: one block (4 waves) per (b,t,u,h) ------------
// S = QK^T/8 via mfma_16x16x32_bf16; softmax in C-layout registers; P round-
// trips through per-wave LDS chunk buffer (C-layout -> A-layout, m120 flow);
// O = P.V via MFMA with V^T staged in LDS.
// LDS: K[208][72] bf16 (29952) + Vt[64][232] bf16 (29696, key cols 196..231
// zeroed) + 4 x P[16][40] bf16 (5120) = 64768 B -> 2 blocks/CU.
__global__ __launch_bounds__(256) void attn_kernel(
    const float* __restrict__ Q, const float* __restrict__ K,
    const float* __restrict__ V, __bf16* __restrict__ av)
{
  __shared__ __bf16 Ks[208 * 72];
  __shared__ __bf16 Vt[64 * 232];
  __shared__ __bf16 Pball[4 * 16 * 40];

  int blk = blockIdx.x;
  int h = blk & 7;
  int r0 = blk >> 3;
  int u = r0 % 12; r0 /= 12;
  int t = r0 % 12;
  int b = r0 / 12;

  const float* Kp = K + ((size_t)(b * 12 + u) * 196) * 512 + h * 64;
  const float* Vp = V + ((size_t)(b * 12 + u) * 196) * 512 + h * 64;
  const float* Qp = Q + ((size_t)(b * 12 + t) * 196) * 512 + h * 64;
  __bf16* avp = av + ((size_t)((b * 12 + t) * 12 + u) * 196) * 512 + h * 64;

  // zero Vt pad columns (keys 196..231) so P*pad is exactly 0, never NaN
  for (int idx = threadIdx.x; idx < 64 * 36; idx += 256) {
    int r = idx / 36;
    int c = idx - r * 36 + 196;
    Vt[r * 232 + c] = (__bf16)0.f;
  }
  // stage K (row-major, stride 72) and V^T (stride 232), fp32 -> bf16
  for (int idx = threadIdx.x; idx < 196 * 16; idx += 256) {
    int r = idx >> 4;
    int c4 = (idx & 15) * 4;
    float4 kv = *(const float4*)&Kp[(size_t)r * 512 + c4];
    float4 vv = *(const float4*)&Vp[(size_t)r * 512 + c4];
    __bf16* kd = &Ks[r * 72 + c4];
    kd[0] = (__bf16)kv.x; kd[1] = (__bf16)kv.y;
    kd[2] = (__bf16)kv.z; kd[3] = (__bf16)kv.w;
    Vt[(c4 + 0) * 232 + r] = (__bf16)vv.x;
    Vt[(c4 + 1) * 232 + r] = (__bf16)vv.y;
    Vt[(c4 + 2) * 232 + r] = (__bf16)vv.z;
    Vt[(c4 + 3) * 232 + r] = (__bf16)vv.w;
  }
  __syncthreads();

  int w = threadIdx.x >> 6, l = threadIdx.x & 63;
  int lm = l & 15, lq = l >> 4;
  __bf16* Pb = Pball + w * (16 * 40);

  for (int qt = w; qt < 13; qt += 4) {
    int q0 = qt * 16;
    // Q A-frags straight from global (rows >=196 read garbage inside ws; the
    // resulting S/P/O rows are never stored and NaN stays within its row)
    const float* qp = Qp + (size_t)(q0 + lm) * 512 + lq * 8;
    float4 qa0 = *(const float4*)qp;
    float4 qa1 = *(const float4*)(qp + 4);
    float4 qb0 = *(const float4*)(qp + 32);
    float4 qb1 = *(const float4*)(qp + 36);
    bfrag8 aq0, aq1;
    aq0[0] = (__bf16)qa0.x; aq0[1] = (__bf16)qa0.y; aq0[2] = (__bf16)qa0.z; aq0[3] = (__bf16)qa0.w;
    aq0[4] = (__bf16)qa1.x; aq0[5] = (__bf16)qa1.y; aq0[6] = (__bf16)qa1.z; aq0[7] = (__bf16)qa1.w;
    aq1[0] = (__bf16)qb0.x; aq1[1] = (__bf16)qb0.y; aq1[2] = (__bf16)qb0.z; aq1[3] = (__bf16)qb0.w;
    aq1[4] = (__bf16)qb1.x; aq1[5] = (__bf16)qb1.y; aq1[6] = (__bf16)qb1.z; aq1[7] = (__bf16)qb1.w;

    ffrag4 S[13];
#pragma unroll
    for (int nt = 0; nt < 13; ++nt) {
      ffrag4 s = {0.f, 0.f, 0.f, 0.f};
      bfrag8 b0 = *(const bfrag8*)&Ks[(nt * 16 + lm) * 72 + lq * 8];
      bfrag8 b1 = *(const bfrag8*)&Ks[(nt * 16 + lm) * 72 + 32 + lq * 8];
      s = __builtin_amdgcn_mfma_f32_16x16x32_bf16(aq0, b0, s, 0, 0, 0);
      s = __builtin_amdgcn_mfma_f32_16x16x32_bf16(aq1, b1, s, 0, 0, 0);
      S[nt] = s;
    }

    // scale + mask pad keys (cols 196..207 live in tile 12, lanes lm>=4)
#pragma unroll
    for (int nt = 0; nt < 13; ++nt) {
#pragma unroll
      for (int r = 0; r < 4; ++r) {
        float s = S[nt][r] * 0.125f;
        if (nt == 12 && lm >= 4) s = -3.0e38f;
        S[nt][r] = s;
      }
    }

    // per-row softmax: row = lq*4 + r; 196 cols live across the 16-lane group
    float sums[4];
#pragma unroll
    for (int r = 0; r < 4; ++r) {
      float mx = -3.0e38f;
#pragma unroll
      for (int nt = 0; nt < 13; ++nt) mx = fmaxf(mx, S[nt][r]);
      mx = fmaxf(mx, __shfl_xor(mx, 1));
      mx = fmaxf(mx, __shfl_xor(mx, 2));
      mx = fmaxf(mx, __shfl_xor(mx, 4));
      mx = fmaxf(mx, __shfl_xor(mx, 8));
      float sum = 0.f;
#pragma unroll
      for (int nt = 0; nt < 13; ++nt) {
        float e = __expf(S[nt][r] - mx);   // masked entries: exp(-huge) = 0
        S[nt][r] = e;
        sum += e;
      }
      sum += __shfl_xor(sum, 1);
      sum += __shfl_xor(sum, 2);
      sum += __shfl_xor(sum, 4);
      sum += __shfl_xor(sum, 8);
      sums[r] = sum;
    }

    // O = P.V over 7 key chunks of 32, P via LDS C->A layout round-trip
    ffrag4 O0 = {0.f,0.f,0.f,0.f}, O1 = O0, O2 = O0, O3 = O0;
    for (int c = 0; c < 7; ++c) {
      int t0 = 2 * c, t1 = 2 * c + 1;
#pragma unroll
      for (int r = 0; r < 4; ++r) {
        int row = lq * 4 + r;
        Pb[row * 40 + lm] = (__bf16)S[t0][r];
        Pb[row * 40 + 16 + lm] = (__bf16)(t1 < 13 ? S[t1][r] : 0.f);
      }
      __threadfence_block();   // same-wave LDS write->read ordering
      bfrag8 pa = *(const bfrag8*)&Pb[lm * 40 + lq * 8];
      bfrag8 v0 = *(const bfrag8*)&Vt[(0 * 16 + lm) * 232 + c * 32 + lq * 8];
      bfrag8 v1 = *(const bfrag8*)&Vt[(1 * 16 + lm) * 232 + c * 32 + lq * 8];
      bfrag8 v2 = *(const bfrag8*)&Vt[(2 * 16 + lm) * 232 + c * 32 + lq * 8];
      bfrag8 v3 = *(const bfrag8*)&Vt[(3 * 16 + lm) * 232 + c * 32 + lq * 8];
      O0 = __builtin_amdgcn_mfma_f32_16x16x32_bf16(pa, v0, O0, 0, 0, 0);
      O1 = __builtin_amdgcn_mfma_f32_16x16x32_bf16(pa, v1, O1, 0, 0, 0);
      O2 = __builtin_amdgcn_mfma_f32_16x16x32_bf16(pa, v2, O2, 0, 0, 0);
      O3 = __builtin_amdgcn_mfma_f32_16x16x32_bf16(pa, v3, O3, 0, 0, 0);
    }

    float inv[4];
#pragma unroll
    for (int r = 0; r < 4; ++r) inv[r] = 1.f / sums[r];

#pragma unroll
    for (int r = 0; r < 4; ++r) {
      int q = q0 + lq * 4 + r;
      if (q < 196) {
        size_t base = (size_t)q * 512 + lm;
        avp[base +  0] = (__bf16)(O0[r] * inv[r]);
        avp[base + 16] = (__bf16)(O1[r] * inv[r]);
        avp[base + 32] = (__bf16)(O2[r] * inv[r]);
        avp[base + 48] = (__bf16)(O3[r] * inv[r]);
      }
    }
  }
}

extern "C" void kernel_launch(void* const* d_in, const int* in_sizes, int n_in,
                              void* d_out, int out_size, void* d_ws, size_t ws_size,
                              hipStream_t stream)
{
  const float* x      = (const float*)d_in[0];
  const float* Wq     = (const float*)d_in[1];
  const float* bq     = (const float*)d_in[2];
  const float* Wk     = (const float*)d_in[3];
  const float* bk     = (const float*)d_in[4];
  const float* Wv     = (const float*)d_in[5];
  const float* bv     = (const float*)d_in[6];
  const float* in_a   = (const float*)d_in[7];
  const float* in_b   = (const float*)d_in[8];
  const float* attn_a = (const float*)d_in[9];
  const float* attn_b = (const float*)d_in[10];
  const float* out_a  = (const float*)d_in[11];
  const float* out_b  = (const float*)d_in[12];
  const float* Wt     = (const float*)d_in[13];
  const float* bt     = (const float*)d_in[14];
  const float* pos    = (const float*)d_in[15];
  const float* W1     = (const float*)d_in[16];
  const float* b1     = (const float*)d_in[17];
  const float* W2     = (const float*)d_in[18];
  const float* b2     = (const float*)d_in[19];

  char* ws = (char*)d_ws;
  const size_t MD = (size_t)9408 * 512;        // 4,816,896 elems
  const size_t fbytes = MD * 4;                // 19,267,584 B
  float* x2   = (float*)(ws);                  // normed input; later reused as x3
  float* Qb   = (float*)(ws + fbytes);         // later reused (with Kb) as h
  float* Kb   = (float*)(ws + 2 * fbytes);
  float* Vb   = (float*)(ws + 3 * fbytes);     // later reused as xmid
  bf16*  av   = (bf16*)(ws + 4 * fbytes);      // B*T*T*P*D bf16 = 115.6 MB
  float* xmid = Vb;
  float* x3   = x2;
  float* hbuf = Qb;                            // 9408 x 1024 f32 over Q+K
  float* out  = (float*)d_out;

  dim3 g8(8, 147), g16(16, 147);

  // 1. x2 = norm(x, in_a, in_b)
  norm_f32_kernel<<<9408, 64, 0, stream>>>(x, x2, in_a, in_b);
  // 2. Q/K/V = x2 @ W^T + b   (layout [(b,t,p), h*64+dh])
  gemm_nt_kernel<<<g8, 256, 0, stream>>>(x2, Wq, bq, Qb, nullptr, 9408, 512, 512, 0);
  gemm_nt_kernel<<<g8, 256, 0, stream>>>(x2, Wk, bk, Kb, nullptr, 9408, 512, 512, 0);
  gemm_nt_kernel<<<g8, 256, 0, stream>>>(x2, Wv, bv, Vb, nullptr, 9408, 512, 512, 0);
  // 3. av[b,t,u,p,:] = softmax(QK^T/8) V   per (b,t,u,h)  -- MFMA flash
  attn_kernel<<<4608, 256, 0, stream>>>(Qb, Kb, Vb, (__bf16*)av);
  // 4. x2p = norm(av, attn_a, attn_b) + pos   (in place, bf16)
  norm_av_kernel<<<112896, 64, 0, stream>>>(av, attn_a, attn_b, pos);
  // 5. xmid = x + gelu( sum_u x2p_u @ Wt[u]^T /12 + sum_u bt[u] )
  gemm_tc_kernel<<<g8, 256, 0, stream>>>(av, Wt, bt, x, xmid);
  // 6. x3 = norm(xmid, out_a, out_b)
  norm_f32_kernel<<<9408, 64, 0, stream>>>(xmid, x3, out_a, out_b);
  // 7. h = gelu(x3 @ W1^T + b1)
  gemm_nt_kernel<<<g16, 256, 0, stream>>>(x3, W1, b1, hbuf, nullptr, 9408, 1024, 512, 1);
  // 8. out = xmid + gelu(h @ W2^T + b2)
  gemm_nt_kernel<<<g8, 256, 0, stream>>>(hbuf, W2, b2, out, xmid, 9408, 512, 1024, 2);
}

// Round 3
// 649.332 us; speedup vs baseline: 5.5648x; 3.0327x over previous
//
#include <hip/hip_runtime.h>
#include <hip/hip_bf16.h>

typedef __hip_bfloat16 bf16;

typedef __bf16 bfrag8 __attribute__((ext_vector_type(8)));
typedef float  ffrag4 __attribute__((ext_vector_type(4)));

// B=4, T=12, P=196, D=512, H=8, DH=64 ; M = B*T*P = 9408
#define EPS 1e-6f

__device__ __forceinline__ float gelu_exact(float v) {
  return 0.5f * v * (1.0f + erff(v * 0.7071067811865475f));
}

__device__ __forceinline__ void async16(const void* g, void* s) {
  __builtin_amdgcn_global_load_lds(
      (const __attribute__((address_space(1))) unsigned int*)g,
      (__attribute__((address_space(3))) unsigned int*)s, 16, 0, 0);
}

struct alignas(16) bf16x8 { bf16 v[8]; };

// ---------------- weight convert f32 -> bf16, packed region ----------------
// [Wqb 262144][Wkb 262144][Wvb 262144][W1b 524288][W2b 524288][Wtb 3145728]
__global__ __launch_bounds__(256) void conv_w_kernel(
    const float* __restrict__ Wq, const float* __restrict__ Wk,
    const float* __restrict__ Wv, const float* __restrict__ W1,
    const float* __restrict__ W2, const float* __restrict__ Wt,
    __bf16* __restrict__ dst)
{
  size_t e = ((size_t)blockIdx.x * 256 + threadIdx.x) * 8;
  const float* src; size_t off;
  if      (e <  262144) { src = Wq; off = e; }
  else if (e <  524288) { src = Wk; off = e -  262144; }
  else if (e <  786432) { src = Wv; off = e -  524288; }
  else if (e < 1310720) { src = W1; off = e -  786432; }
  else if (e < 1835008) { src = W2; off = e - 1310720; }
  else if (e < 4980736) { src = Wt; off = e - 1835008; }
  else return;
  float4 f0 = *(const float4*)(src + off);
  float4 f1 = *(const float4*)(src + off + 4);
  bfrag8 o;
  o[0] = (__bf16)f0.x; o[1] = (__bf16)f0.y; o[2] = (__bf16)f0.z; o[3] = (__bf16)f0.w;
  o[4] = (__bf16)f1.x; o[5] = (__bf16)f1.y; o[6] = (__bf16)f1.z; o[7] = (__bf16)f1.w;
  *(bfrag8*)(dst + e) = o;
}

__global__ __launch_bounds__(512) void sum_bt_kernel(
    const float* __restrict__ bt, float* __restrict__ sbt)
{
  int n = threadIdx.x;
  float s = 0.f;
#pragma unroll
  for (int u = 0; u < 12; ++u) s += bt[u * 512 + n];
  sbt[n] = s;
}

// ------------- LayerNorm f32 -> bf16, one 64-thread block per row of 512 ----
__global__ __launch_bounds__(64) void norm_f32_to_bf16_kernel(
    const float* __restrict__ in, __bf16* __restrict__ out,
    const float* __restrict__ alpha, const float* __restrict__ beta)
{
  size_t row = blockIdx.x;
  int l = threadIdx.x;
  const float* r = in + row * 512 + l * 8;
  float4 v0 = *(const float4*)(r);
  float4 v1 = *(const float4*)(r + 4);
  float f[8] = {v0.x, v0.y, v0.z, v0.w, v1.x, v1.y, v1.z, v1.w};
  float s = 0.f, ss = 0.f;
#pragma unroll
  for (int q = 0; q < 8; ++q) { s += f[q]; ss += f[q] * f[q]; }
#pragma unroll
  for (int off = 32; off; off >>= 1) { s += __shfl_xor(s, off); ss += __shfl_xor(ss, off); }
  float mu = s * (1.f / 512.f);
  float var = fmaxf((ss - 512.f * mu * mu) * (1.f / 511.f), 0.f);
  float inv = 1.f / (sqrtf(var) + EPS);
  const float* al = alpha + l * 8;
  const float* be = beta + l * 8;
  float4 a0 = *(const float4*)al, a1 = *(const float4*)(al + 4);
  float4 b0 = *(const float4*)be, b1 = *(const float4*)(be + 4);
  float aa[8] = {a0.x, a0.y, a0.z, a0.w, a1.x, a1.y, a1.z, a1.w};
  float bb[8] = {b0.x, b0.y, b0.z, b0.w, b1.x, b1.y, b1.z, b1.w};
  bfrag8 o;
#pragma unroll
  for (int q = 0; q < 8; ++q) o[q] = (__bf16)(aa[q] * (f[q] - mu) * inv + bb[q]);
  *(bfrag8*)(out + row * 512 + l * 8) = o;
}

// ------------- LayerNorm bf16 in-place + pos add (x2p = norm(av)+pos) -------
__global__ __launch_bounds__(64) void norm_av_kernel(
    bf16* __restrict__ av, const float* __restrict__ alpha,
    const float* __restrict__ beta, const float* __restrict__ pos)
{
  size_t row = blockIdx.x;          // [0, B*T*T*P)
  int l = threadIdx.x;
  bf16* r = av + row * 512 + (size_t)l * 8;
  bf16x8 ib = *(const bf16x8*)r;
  float f[8];
#pragma unroll
  for (int q = 0; q < 8; ++q) f[q] = __bfloat162float(ib.v[q]);
  float s = 0.f, ss = 0.f;
#pragma unroll
  for (int q = 0; q < 8; ++q) { s += f[q]; ss += f[q] * f[q]; }
#pragma unroll
  for (int off = 32; off; off >>= 1) { s += __shfl_xor(s, off); ss += __shfl_xor(ss, off); }
  float mu = s * (1.f / 512.f);
  float var = fmaxf((ss - 512.f * mu * mu) * (1.f / 511.f), 0.f);
  float inv = 1.f / (sqrtf(var) + EPS);
  size_t prow = row % 28224;        // T*T*P  (pos broadcasts over batch)
  const float* pr = pos + prow * 512 + l * 8;
  float4 p0 = *(const float4*)pr, p1 = *(const float4*)(pr + 4);
  const float* al = alpha + l * 8;
  const float* be = beta + l * 8;
  float4 a0 = *(const float4*)al, a1 = *(const float4*)(al + 4);
  float4 b0 = *(const float4*)be, b1 = *(const float4*)(be + 4);
  float pa[8] = {p0.x, p0.y, p0.z, p0.w, p1.x, p1.y, p1.z, p1.w};
  float aa[8] = {a0.x, a0.y, a0.z, a0.w, a1.x, a1.y, a1.z, a1.w};
  float bb[8] = {b0.x, b0.y, b0.z, b0.w, b1.x, b1.y, b1.z, b1.w};
  bf16x8 ob;
#pragma unroll
  for (int q = 0; q < 8; ++q)
    ob.v[q] = __float2bfloat16(aa[q] * (f[q] - mu) * inv + bb[q] + pa[q]);
  *(bf16x8*)r = ob;
}

// ------------- MFMA NT GEMM, 128x128 tile, BK=32, global_load_lds staging ---
// mode 0: fused QKV (N=1536, B/bias/out selected by n-block), out bf16 +bias
// mode 1: MLP1 (N=1024), out bf16 = gelu(acc+bias)
// mode 2: MLP2 (N=512),  out f32 = res + gelu(acc+bias)
__global__ __launch_bounds__(256) void mfma_nt_kernel(
    const __bf16* __restrict__ A,
    const __bf16* __restrict__ Bq, const __bf16* __restrict__ Bk,
    const __bf16* __restrict__ Bv,
    const float* __restrict__ bq, const float* __restrict__ bk,
    const float* __restrict__ bv,
    __bf16* __restrict__ oq, __bf16* __restrict__ ok, __bf16* __restrict__ ov,
    const float* __restrict__ res, float* __restrict__ fout,
    int K, int mode)
{
  __shared__ __bf16 As[128 * 32];
  __shared__ __bf16 Bs[128 * 32];
  int tid = threadIdx.x;
  int m0 = blockIdx.y * 128;
  int n0g = blockIdx.x * 128;

  const __bf16* Bsel; const float* biassel; __bf16* osel; int ncol0;
  if (mode == 0) {
    int sel = n0g >> 9;
    Bsel = sel == 0 ? Bq : (sel == 1 ? Bk : Bv);
    biassel = sel == 0 ? bq : (sel == 1 ? bk : bv);
    osel = sel == 0 ? oq : (sel == 1 ? ok : ov);
    ncol0 = n0g & 511;
  } else {
    Bsel = Bq; biassel = bq; osel = oq; ncol0 = n0g;
  }

  int srow = tid >> 2, scol = (tid & 3) * 8;
  int r0 = m0 + srow;      if (r0 > 9407) r0 = 9407;
  int r1 = m0 + 64 + srow; if (r1 > 9407) r1 = 9407;
  const __bf16* a0 = A + (size_t)r0 * K + scol;
  const __bf16* a1 = A + (size_t)r1 * K + scol;
  const __bf16* b0 = Bsel + (size_t)(ncol0 + srow) * K + scol;
  const __bf16* b1 = Bsel + (size_t)(ncol0 + 64 + srow) * K + scol;
  char* sa0 = (char*)As + tid * 16;
  char* sa1 = (char*)As + 4096 + tid * 16;
  char* sb0 = (char*)Bs + tid * 16;
  char* sb1 = (char*)Bs + 4096 + tid * 16;

  int l = tid & 63, w = tid >> 6;
  int lm = l & 15, lq = l >> 4;
  int wm = w >> 1, wn = w & 1;

  ffrag4 acc[4][4] = {};
  for (int k0 = 0; k0 < K; k0 += 32) {
    __syncthreads();
    async16(a0 + k0, sa0);
    async16(a1 + k0, sa1);
    async16(b0 + k0, sb0);
    async16(b1 + k0, sb1);
    __syncthreads();
    bfrag8 af[4], bfr[4];
#pragma unroll
    for (int i = 0; i < 4; ++i)
      af[i] = *(const bfrag8*)&As[(wm * 64 + i * 16 + lm) * 32 + lq * 8];
#pragma unroll
    for (int j = 0; j < 4; ++j)
      bfr[j] = *(const bfrag8*)&Bs[(wn * 64 + j * 16 + lm) * 32 + lq * 8];
#pragma unroll
    for (int i = 0; i < 4; ++i)
#pragma unroll
      for (int j = 0; j < 4; ++j)
        acc[i][j] = __builtin_amdgcn_mfma_f32_16x16x32_bf16(af[i], bfr[j], acc[i][j], 0, 0, 0);
  }

#pragma unroll
  for (int i = 0; i < 4; ++i) {
    int mbase = m0 + wm * 64 + i * 16 + lq * 4;
#pragma unroll
    for (int j = 0; j < 4; ++j) {
      int n = ncol0 + wn * 64 + j * 16 + lm;
      float bj = biassel[n];
#pragma unroll
      for (int r = 0; r < 4; ++r) {
        int mr = mbase + r;
        if (mr < 9408) {
          float v = acc[i][j][r] + bj;
          if (mode == 0)      osel[(size_t)mr * 512 + n] = (__bf16)v;
          else if (mode == 1) osel[(size_t)mr * 1024 + n] = (__bf16)gelu_exact(v);
          else                fout[(size_t)mr * 512 + n] =
                                res[(size_t)mr * 512 + n] + gelu_exact(v);
        }
      }
    }
  }
}

// ------- temporal mixing via MFMA: xmid = x + gelu(sum_u x2p_u@Wt_u^T /12 + sbt)
// M=9408, N=512, K=12*512; A rows decompose (btq,p) per row.
__global__ __launch_bounds__(256) void mfma_tc_kernel(
    const __bf16* __restrict__ X2p, const __bf16* __restrict__ Wtb,
    const float* __restrict__ sbt, const float* __restrict__ xin,
    float* __restrict__ xmid)
{
  __shared__ __bf16 As[128 * 32];
  __shared__ __bf16 Bs[128 * 32];
  int tid = threadIdx.x;
  int m0 = blockIdx.y * 128;
  int n0 = blockIdx.x * 128;

  int srow = tid >> 2, scol = (tid & 3) * 8;
  int r0 = m0 + srow;      if (r0 > 9407) r0 = 9407;
  int r1 = m0 + 64 + srow; if (r1 > 9407) r1 = 9407;
  int btq0 = r0 / 196, p0 = r0 - btq0 * 196;
  int btq1 = r1 / 196, p1 = r1 - btq1 * 196;
  const __bf16* a0 = X2p + (size_t)btq0 * 1204224 + (size_t)p0 * 512 + scol;
  const __bf16* a1 = X2p + (size_t)btq1 * 1204224 + (size_t)p1 * 512 + scol;
  const __bf16* b0 = Wtb + (size_t)(n0 + srow) * 512 + scol;
  const __bf16* b1 = Wtb + (size_t)(n0 + 64 + srow) * 512 + scol;
  char* sa0 = (char*)As + tid * 16;
  char* sa1 = (char*)As + 4096 + tid * 16;
  char* sb0 = (char*)Bs + tid * 16;
  char* sb1 = (char*)Bs + 4096 + tid * 16;

  int l = tid & 63, w = tid >> 6;
  int lm = l & 15, lq = l >> 4;
  int wm = w >> 1, wn = w & 1;

  ffrag4 acc[4][4] = {};
  for (int u = 0; u < 12; ++u) {
    size_t au = (size_t)u * 100352;   // u * P * D   (elems)
    size_t bu = (size_t)u * 262144;   // u * D * D   (elems)
    for (int d0 = 0; d0 < 512; d0 += 32) {
      __syncthreads();
      async16(a0 + au + d0, sa0);
      async16(a1 + au + d0, sa1);
      async16(b0 + bu + d0, sb0);
      async16(b1 + bu + d0, sb1);
      __syncthreads();
      bfrag8 af[4], bfr[4];
#pragma unroll
      for (int i = 0; i < 4; ++i)
        af[i] = *(const bfrag8*)&As[(wm * 64 + i * 16 + lm) * 32 + lq * 8];
#pragma unroll
      for (int j = 0; j < 4; ++j)
        bfr[j] = *(const bfrag8*)&Bs[(wn * 64 + j * 16 + lm) * 32 + lq * 8];
#pragma unroll
      for (int i = 0; i < 4; ++i)
#pragma unroll
        for (int j = 0; j < 4; ++j)
          acc[i][j] = __builtin_amdgcn_mfma_f32_16x16x32_bf16(af[i], bfr[j], acc[i][j], 0, 0, 0);
    }
  }

#pragma unroll
  for (int i = 0; i < 4; ++i) {
    int mbase = m0 + wm * 64 + i * 16 + lq * 4;
#pragma unroll
    for (int j = 0; j < 4; ++j) {
      int n = n0 + wn * 64 + j * 16 + lm;
      float bj = sbt[n];
#pragma unroll
      for (int r = 0; r < 4; ++r) {
        int mr = mbase + r;
        if (mr < 9408) {
          float v = acc[i][j][r] * (1.f / 12.f) + bj;
          xmid[(size_t)mr * 512 + n] = xin[(size_t)mr * 512 + n] + gelu_exact(v);
        }
      }
    }
  }
}

// ------------- MFMA attention: one block (4 waves) per (b,t,u,h) ------------
__global__ __launch_bounds__(256) void attn_kernel(
    const __bf16* __restrict__ Q, const __bf16* __restrict__ K,
    const __bf16* __restrict__ V, __bf16* __restrict__ av)
{
  __shared__ __bf16 Ks[208 * 72];
  __shared__ __bf16 Vt[64 * 232];
  __shared__ __bf16 Pball[4 * 16 * 40];

  int blk = blockIdx.x;
  int h = blk & 7;
  int r0 = blk >> 3;
  int u = r0 % 12; r0 /= 12;
  int t = r0 % 12;
  int b = r0 / 12;

  const __bf16* Kp = K + ((size_t)(b * 12 + u) * 196) * 512 + h * 64;
  const __bf16* Vp = V + ((size_t)(b * 12 + u) * 196) * 512 + h * 64;
  const __bf16* Qp = Q + ((size_t)(b * 12 + t) * 196) * 512 + h * 64;
  __bf16* avp = av + ((size_t)((b * 12 + t) * 12 + u) * 196) * 512 + h * 64;

  for (int idx = threadIdx.x; idx < 64 * 36; idx += 256) {
    int r = idx / 36;
    int c = idx - r * 36 + 196;
    Vt[r * 232 + c] = (__bf16)0.f;
  }
  for (int idx = threadIdx.x; idx < 196 * 8; idx += 256) {
    int r = idx >> 3;
    int c8 = (idx & 7) * 8;
    bfrag8 kv = *(const bfrag8*)&Kp[(size_t)r * 512 + c8];
    bfrag8 vv = *(const bfrag8*)&Vp[(size_t)r * 512 + c8];
    *(bfrag8*)&Ks[r * 72 + c8] = kv;
#pragma unroll
    for (int e = 0; e < 8; ++e) Vt[(c8 + e) * 232 + r] = vv[e];
  }
  __syncthreads();

  int w = threadIdx.x >> 6, l = threadIdx.x & 63;
  int lm = l & 15, lq = l >> 4;
  __bf16* Pb = Pball + w * (16 * 40);

  for (int qt = w; qt < 13; qt += 4) {
    int q0 = qt * 16;
    const __bf16* qp = Qp + (size_t)(q0 + lm) * 512 + lq * 8;
    bfrag8 aq0 = *(const bfrag8*)qp;
    bfrag8 aq1 = *(const bfrag8*)(qp + 32);

    ffrag4 S[13];
#pragma unroll
    for (int nt = 0; nt < 13; ++nt) {
      ffrag4 s = {0.f, 0.f, 0.f, 0.f};
      bfrag8 kb0 = *(const bfrag8*)&Ks[(nt * 16 + lm) * 72 + lq * 8];
      bfrag8 kb1 = *(const bfrag8*)&Ks[(nt * 16 + lm) * 72 + 32 + lq * 8];
      s = __builtin_amdgcn_mfma_f32_16x16x32_bf16(aq0, kb0, s, 0, 0, 0);
      s = __builtin_amdgcn_mfma_f32_16x16x32_bf16(aq1, kb1, s, 0, 0, 0);
      S[nt] = s;
    }

#pragma unroll
    for (int nt = 0; nt < 13; ++nt) {
#pragma unroll
      for (int r = 0; r < 4; ++r) {
        float s = S[nt][r] * 0.125f;
        if (nt == 12 && lm >= 4) s = -3.0e38f;
        S[nt][r] = s;
      }
    }

    float sums[4];
#pragma unroll
    for (int r = 0; r < 4; ++r) {
      float mx = -3.0e38f;
#pragma unroll
      for (int nt = 0; nt < 13; ++nt) mx = fmaxf(mx, S[nt][r]);
      mx = fmaxf(mx, __shfl_xor(mx, 1));
      mx = fmaxf(mx, __shfl_xor(mx, 2));
      mx = fmaxf(mx, __shfl_xor(mx, 4));
      mx = fmaxf(mx, __shfl_xor(mx, 8));
      float sum = 0.f;
#pragma unroll
      for (int nt = 0; nt < 13; ++nt) {
        float e = __expf(S[nt][r] - mx);
        S[nt][r] = e;
        sum += e;
      }
      sum += __shfl_xor(sum, 1);
      sum += __shfl_xor(sum, 2);
      sum += __shfl_xor(sum, 4);
      sum += __shfl_xor(sum, 8);
      sums[r] = sum;
    }

    ffrag4 O0 = {0.f, 0.f, 0.f, 0.f}, O1 = O0, O2 = O0, O3 = O0;
    for (int c = 0; c < 7; ++c) {
      int t0 = 2 * c, t1 = 2 * c + 1;
#pragma unroll
      for (int r = 0; r < 4; ++r) {
        int row = lq * 4 + r;
        Pb[row * 40 + lm] = (__bf16)S[t0][r];
        Pb[row * 40 + 16 + lm] = (__bf16)(t1 < 13 ? S[t1][r] : 0.f);
      }
      __threadfence_block();
      bfrag8 pa = *(const bfrag8*)&Pb[lm * 40 + lq * 8];
      bfrag8 v0 = *(const bfrag8*)&Vt[(0 * 16 + lm) * 232 + c * 32 + lq * 8];
      bfrag8 v1 = *(const bfrag8*)&Vt[(1 * 16 + lm) * 232 + c * 32 + lq * 8];
      bfrag8 v2 = *(const bfrag8*)&Vt[(2 * 16 + lm) * 232 + c * 32 + lq * 8];
      bfrag8 v3 = *(const bfrag8*)&Vt[(3 * 16 + lm) * 232 + c * 32 + lq * 8];
      O0 = __builtin_amdgcn_mfma_f32_16x16x32_bf16(pa, v0, O0, 0, 0, 0);
      O1 = __builtin_amdgcn_mfma_f32_16x16x32_bf16(pa, v1, O1, 0, 0, 0);
      O2 = __builtin_amdgcn_mfma_f32_16x16x32_bf16(pa, v2, O2, 0, 0, 0);
      O3 = __builtin_amdgcn_mfma_f32_16x16x32_bf16(pa, v3, O3, 0, 0, 0);
    }

    float inv[4];
#pragma unroll
    for (int r = 0; r < 4; ++r) inv[r] = 1.f / sums[r];

#pragma unroll
    for (int r = 0; r < 4; ++r) {
      int q = q0 + lq * 4 + r;
      if (q < 196) {
        size_t base = (size_t)q * 512 + lm;
        avp[base +  0] = (__bf16)(O0[r] * inv[r]);
        avp[base + 16] = (__bf16)(O1[r] * inv[r]);
        avp[base + 32] = (__bf16)(O2[r] * inv[r]);
        avp[base + 48] = (__bf16)(O3[r] * inv[r]);
      }
    }
  }
}

extern "C" void kernel_launch(void* const* d_in, const int* in_sizes, int n_in,
                              void* d_out, int out_size, void* d_ws, size_t ws_size,
                              hipStream_t stream)
{
  const float* x      = (const float*)d_in[0];
  const float* Wq     = (const float*)d_in[1];
  const float* bq     = (const float*)d_in[2];
  const float* Wk     = (const float*)d_in[3];
  const float* bk     = (const float*)d_in[4];
  const float* Wv     = (const float*)d_in[5];
  const float* bv     = (const float*)d_in[6];
  const float* in_a   = (const float*)d_in[7];
  const float* in_b   = (const float*)d_in[8];
  const float* attn_a = (const float*)d_in[9];
  const float* attn_b = (const float*)d_in[10];
  const float* out_a  = (const float*)d_in[11];
  const float* out_b  = (const float*)d_in[12];
  const float* Wt     = (const float*)d_in[13];
  const float* bt     = (const float*)d_in[14];
  const float* pos    = (const float*)d_in[15];
  const float* W1     = (const float*)d_in[16];
  const float* b1     = (const float*)d_in[17];
  const float* W2     = (const float*)d_in[18];
  const float* b2     = (const float*)d_in[19];

  char* ws = (char*)d_ws;
  const size_t bfb = (size_t)9408 * 512 * 2;       // 9,633,792 B (bf16 MxD)
  // layout (bytes):
  __bf16* x2b  = (__bf16*)(ws);                    // [0, bfb)
  __bf16* Qb   = (__bf16*)(ws + bfb);              // [bfb, 2bfb)
  __bf16* Kb   = (__bf16*)(ws + 2 * bfb);
  __bf16* Vb   = (__bf16*)(ws + 3 * bfb);
  __bf16* av   = (__bf16*)(ws + 4 * bfb);          // 115,605,504 B
  char*   wreg = ws + 4 * bfb + (size_t)115605504; // weights bf16, 9,961,472 B
  __bf16* Wqb  = (__bf16*)(wreg);
  __bf16* Wkb  = (__bf16*)(wreg) + 262144;
  __bf16* Wvb  = (__bf16*)(wreg) + 524288;
  __bf16* W1b  = (__bf16*)(wreg) + 786432;
  __bf16* W2b  = (__bf16*)(wreg) + 1310720;
  __bf16* Wtb  = (__bf16*)(wreg) + 1835008;
  float*  sbt  = (float*)(wreg + 9961472);         // 2048 B
  // overlays (stream-ordered lifetimes):
  float*  xmid = (float*)(ws);                     // over x2b+Qb (19.27 MB)
  __bf16* x3b  = (__bf16*)(ws + 2 * bfb);          // over Kb
  __bf16* hb   = (__bf16*)(ws + 4 * bfb);          // over av (19.27 MB)
  float*  out  = (float*)d_out;

  // 0. weight conversion + bias-sum (tiny)
  conv_w_kernel<<<2432, 256, 0, stream>>>(Wq, Wk, Wv, W1, W2, Wt, (__bf16*)wreg);
  sum_bt_kernel<<<1, 512, 0, stream>>>(bt, sbt);
  // 1. x2b = norm(x) (bf16)
  norm_f32_to_bf16_kernel<<<9408, 64, 0, stream>>>(x, x2b, in_a, in_b);
  // 2. fused QKV GEMM (MFMA)
  mfma_nt_kernel<<<dim3(12, 74), 256, 0, stream>>>(
      x2b, Wqb, Wkb, Wvb, bq, bk, bv, Qb, Kb, Vb, nullptr, nullptr, 512, 0);
  // 3. attention
  attn_kernel<<<4608, 256, 0, stream>>>(Qb, Kb, Vb, av);
  // 4. x2p = norm(av) + pos (in place, bf16)
  norm_av_kernel<<<112896, 64, 0, stream>>>((bf16*)av, attn_a, attn_b, pos);
  // 5. temporal mixing (MFMA) -> xmid f32
  mfma_tc_kernel<<<dim3(4, 74), 256, 0, stream>>>(av, Wtb, sbt, x, xmid);
  // 6. x3b = norm(xmid) (bf16)
  norm_f32_to_bf16_kernel<<<9408, 64, 0, stream>>>(xmid, x3b, out_a, out_b);
  // 7. h = gelu(x3 @ W1^T + b1) (MFMA, bf16 out)
  mfma_nt_kernel<<<dim3(8, 74), 256, 0, stream>>>(
      x3b, W1b, nullptr, nullptr, b1, nullptr, nullptr, hb, nullptr, nullptr,
      nullptr, nullptr, 512, 1);
  // 8. out = xmid + gelu(h @ W2^T + b2) (MFMA, f32 out)
  mfma_nt_kernel<<<dim3(4, 74), 256, 0, stream>>>(
      hb, W2b, nullptr, nullptr, b2, nullptr, nullptr, nullptr, nullptr, nullptr,
      xmid, out, 1024, 2);
}

// Round 4
// 634.650 us; speedup vs baseline: 5.6935x; 1.0231x over previous
//
#include <hip/hip_runtime.h>
#include <hip/hip_bf16.h>

typedef __hip_bfloat16 bf16;

typedef __bf16 bfrag8 __attribute__((ext_vector_type(8)));
typedef float  ffrag4 __attribute__((ext_vector_type(4)));

// B=4, T=12, P=196, D=512, H=8, DH=64 ; M = B*T*P = 9408
#define EPS 1e-6f

__device__ __forceinline__ float gelu_exact(float v) {
  return 0.5f * v * (1.0f + erff(v * 0.7071067811865475f));
}

__device__ __forceinline__ void async16(const void* g, void* s) {
  __builtin_amdgcn_global_load_lds(
      (const __attribute__((address_space(1))) unsigned int*)g,
      (__attribute__((address_space(3))) unsigned int*)s, 16, 0, 0);
}

struct alignas(16) bf16x8 { bf16 v[8]; };
struct alignas(4)  bf16p2 { __bf16 v[2]; };

// ---------------- weight convert f32 -> bf16, packed region ----------------
__global__ __launch_bounds__(256) void conv_w_kernel(
    const float* __restrict__ Wq, const float* __restrict__ Wk,
    const float* __restrict__ Wv, const float* __restrict__ W1,
    const float* __restrict__ W2, const float* __restrict__ Wt,
    __bf16* __restrict__ dst)
{
  size_t e = ((size_t)blockIdx.x * 256 + threadIdx.x) * 8;
  const float* src; size_t off;
  if      (e <  262144) { src = Wq; off = e; }
  else if (e <  524288) { src = Wk; off = e -  262144; }
  else if (e <  786432) { src = Wv; off = e -  524288; }
  else if (e < 1310720) { src = W1; off = e -  786432; }
  else if (e < 1835008) { src = W2; off = e - 1310720; }
  else if (e < 4980736) { src = Wt; off = e - 1835008; }
  else return;
  float4 f0 = *(const float4*)(src + off);
  float4 f1 = *(const float4*)(src + off + 4);
  bfrag8 o;
  o[0] = (__bf16)f0.x; o[1] = (__bf16)f0.y; o[2] = (__bf16)f0.z; o[3] = (__bf16)f0.w;
  o[4] = (__bf16)f1.x; o[5] = (__bf16)f1.y; o[6] = (__bf16)f1.z; o[7] = (__bf16)f1.w;
  *(bfrag8*)(dst + e) = o;
}

__global__ __launch_bounds__(512) void sum_bt_kernel(
    const float* __restrict__ bt, float* __restrict__ sbt)
{
  int n = threadIdx.x;
  float s = 0.f;
#pragma unroll
  for (int u = 0; u < 12; ++u) s += bt[u * 512 + n];
  sbt[n] = s;
}

// ------------- LayerNorm f32 -> bf16, one 64-thread block per row of 512 ----
__global__ __launch_bounds__(64) void norm_f32_to_bf16_kernel(
    const float* __restrict__ in, __bf16* __restrict__ out,
    const float* __restrict__ alpha, const float* __restrict__ beta)
{
  size_t row = blockIdx.x;
  int l = threadIdx.x;
  const float* r = in + row * 512 + l * 8;
  float4 v0 = *(const float4*)(r);
  float4 v1 = *(const float4*)(r + 4);
  float f[8] = {v0.x, v0.y, v0.z, v0.w, v1.x, v1.y, v1.z, v1.w};
  float s = 0.f, ss = 0.f;
#pragma unroll
  for (int q = 0; q < 8; ++q) { s += f[q]; ss += f[q] * f[q]; }
#pragma unroll
  for (int off = 32; off; off >>= 1) { s += __shfl_xor(s, off); ss += __shfl_xor(ss, off); }
  float mu = s * (1.f / 512.f);
  float var = fmaxf((ss - 512.f * mu * mu) * (1.f / 511.f), 0.f);
  float inv = 1.f / (sqrtf(var) + EPS);
  const float* al = alpha + l * 8;
  const float* be = beta + l * 8;
  float4 a0 = *(const float4*)al, a1 = *(const float4*)(al + 4);
  float4 b0 = *(const float4*)be, b1 = *(const float4*)(be + 4);
  float aa[8] = {a0.x, a0.y, a0.z, a0.w, a1.x, a1.y, a1.z, a1.w};
  float bb[8] = {b0.x, b0.y, b0.z, b0.w, b1.x, b1.y, b1.z, b1.w};
  bfrag8 o;
#pragma unroll
  for (int q = 0; q < 8; ++q) o[q] = (__bf16)(aa[q] * (f[q] - mu) * inv + bb[q]);
  *(bfrag8*)(out + row * 512 + l * 8) = o;
}

// ------------- LayerNorm bf16 in-place + pos add (x2p = norm(av)+pos) -------
__global__ __launch_bounds__(64) void norm_av_kernel(
    bf16* __restrict__ av, const float* __restrict__ alpha,
    const float* __restrict__ beta, const float* __restrict__ pos)
{
  size_t row = blockIdx.x;          // [0, B*T*T*P)
  int l = threadIdx.x;
  bf16* r = av + row * 512 + (size_t)l * 8;
  bf16x8 ib = *(const bf16x8*)r;
  float f[8];
#pragma unroll
  for (int q = 0; q < 8; ++q) f[q] = __bfloat162float(ib.v[q]);
  float s = 0.f, ss = 0.f;
#pragma unroll
  for (int q = 0; q < 8; ++q) { s += f[q]; ss += f[q] * f[q]; }
#pragma unroll
  for (int off = 32; off; off >>= 1) { s += __shfl_xor(s, off); ss += __shfl_xor(ss, off); }
  float mu = s * (1.f / 512.f);
  float var = fmaxf((ss - 512.f * mu * mu) * (1.f / 511.f), 0.f);
  float inv = 1.f / (sqrtf(var) + EPS);
  size_t prow = row % 28224;        // T*T*P  (pos broadcasts over batch)
  const float* pr = pos + prow * 512 + l * 8;
  float4 p0 = *(const float4*)pr, p1 = *(const float4*)(pr + 4);
  const float* al = alpha + l * 8;
  const float* be = beta + l * 8;
  float4 a0 = *(const float4*)al, a1 = *(const float4*)(al + 4);
  float4 b0 = *(const float4*)be, b1 = *(const float4*)(be + 4);
  float pa[8] = {p0.x, p0.y, p0.z, p0.w, p1.x, p1.y, p1.z, p1.w};
  float aa[8] = {a0.x, a0.y, a0.z, a0.w, a1.x, a1.y, a1.z, a1.w};
  float bb[8] = {b0.x, b0.y, b0.z, b0.w, b1.x, b1.y, b1.z, b1.w};
  bf16x8 ob;
#pragma unroll
  for (int q = 0; q < 8; ++q)
    ob.v[q] = __float2bfloat16(aa[q] * (f[q] - mu) * inv + bb[q] + pa[q]);
  *(bf16x8*)r = ob;
}

// ------------- MFMA NT GEMM, 128x128 tile, BK=32, global_load_lds staging ---
// mode 0: fused QKV (N=1536, B/bias/out selected by n-block), out bf16 +bias
// mode 1: MLP1 (N=1024), out bf16 = gelu(acc+bias)
// mode 2: MLP2 (N=512),  out f32 = res + gelu(acc+bias)
__global__ __launch_bounds__(256) void mfma_nt_kernel(
    const __bf16* __restrict__ A,
    const __bf16* __restrict__ Bq, const __bf16* __restrict__ Bk,
    const __bf16* __restrict__ Bv,
    const float* __restrict__ bq, const float* __restrict__ bk,
    const float* __restrict__ bv,
    __bf16* __restrict__ oq, __bf16* __restrict__ ok, __bf16* __restrict__ ov,
    const float* __restrict__ res, float* __restrict__ fout,
    int K, int mode)
{
  __shared__ __bf16 As[128 * 32];
  __shared__ __bf16 Bs[128 * 32];
  int tid = threadIdx.x;
  int m0 = blockIdx.y * 128;
  int n0g = blockIdx.x * 128;

  const __bf16* Bsel; const float* biassel; __bf16* osel; int ncol0;
  if (mode == 0) {
    int sel = n0g >> 9;
    Bsel = sel == 0 ? Bq : (sel == 1 ? Bk : Bv);
    biassel = sel == 0 ? bq : (sel == 1 ? bk : bv);
    osel = sel == 0 ? oq : (sel == 1 ? ok : ov);
    ncol0 = n0g & 511;
  } else {
    Bsel = Bq; biassel = bq; osel = oq; ncol0 = n0g;
  }

  int srow = tid >> 2, scol = (tid & 3) * 8;
  int r0 = m0 + srow;      if (r0 > 9407) r0 = 9407;
  int r1 = m0 + 64 + srow; if (r1 > 9407) r1 = 9407;
  const __bf16* a0 = A + (size_t)r0 * K + scol;
  const __bf16* a1 = A + (size_t)r1 * K + scol;
  const __bf16* b0 = Bsel + (size_t)(ncol0 + srow) * K + scol;
  const __bf16* b1 = Bsel + (size_t)(ncol0 + 64 + srow) * K + scol;
  char* sa0 = (char*)As + tid * 16;
  char* sa1 = (char*)As + 4096 + tid * 16;
  char* sb0 = (char*)Bs + tid * 16;
  char* sb1 = (char*)Bs + 4096 + tid * 16;

  int l = tid & 63, w = tid >> 6;
  int lm = l & 15, lq = l >> 4;
  int wm = w >> 1, wn = w & 1;

  ffrag4 acc[4][4] = {};
  for (int k0 = 0; k0 < K; k0 += 32) {
    __syncthreads();
    async16(a0 + k0, sa0);
    async16(a1 + k0, sa1);
    async16(b0 + k0, sb0);
    async16(b1 + k0, sb1);
    __syncthreads();
    bfrag8 af[4], bfr[4];
#pragma unroll
    for (int i = 0; i < 4; ++i)
      af[i] = *(const bfrag8*)&As[(wm * 64 + i * 16 + lm) * 32 + lq * 8];
#pragma unroll
    for (int j = 0; j < 4; ++j)
      bfr[j] = *(const bfrag8*)&Bs[(wn * 64 + j * 16 + lm) * 32 + lq * 8];
#pragma unroll
    for (int i = 0; i < 4; ++i)
#pragma unroll
      for (int j = 0; j < 4; ++j)
        acc[i][j] = __builtin_amdgcn_mfma_f32_16x16x32_bf16(af[i], bfr[j], acc[i][j], 0, 0, 0);
  }

#pragma unroll
  for (int i = 0; i < 4; ++i) {
    int mbase = m0 + wm * 64 + i * 16 + lq * 4;
#pragma unroll
    for (int j = 0; j < 4; ++j) {
      int n = ncol0 + wn * 64 + j * 16 + lm;
      float bj = biassel[n];
#pragma unroll
      for (int r = 0; r < 4; ++r) {
        int mr = mbase + r;
        if (mr < 9408) {
          float v = acc[i][j][r] + bj;
          if (mode == 0)      osel[(size_t)mr * 512 + n] = (__bf16)v;
          else if (mode == 1) osel[(size_t)mr * 1024 + n] = (__bf16)gelu_exact(v);
          else                fout[(size_t)mr * 512 + n] =
                                res[(size_t)mr * 512 + n] + gelu_exact(v);
        }
      }
    }
  }
}

// ------- temporal mixing via MFMA: xmid = x + gelu(sum_u x2p_u@Wt_u^T /12 + sbt)
__global__ __launch_bounds__(256) void mfma_tc_kernel(
    const __bf16* __restrict__ X2p, const __bf16* __restrict__ Wtb,
    const float* __restrict__ sbt, const float* __restrict__ xin,
    float* __restrict__ xmid)
{
  __shared__ __bf16 As[128 * 32];
  __shared__ __bf16 Bs[128 * 32];
  int tid = threadIdx.x;
  int m0 = blockIdx.y * 128;
  int n0 = blockIdx.x * 128;

  int srow = tid >> 2, scol = (tid & 3) * 8;
  int r0 = m0 + srow;      if (r0 > 9407) r0 = 9407;
  int r1 = m0 + 64 + srow; if (r1 > 9407) r1 = 9407;
  int btq0 = r0 / 196, p0 = r0 - btq0 * 196;
  int btq1 = r1 / 196, p1 = r1 - btq1 * 196;
  const __bf16* a0 = X2p + (size_t)btq0 * 1204224 + (size_t)p0 * 512 + scol;
  const __bf16* a1 = X2p + (size_t)btq1 * 1204224 + (size_t)p1 * 512 + scol;
  const __bf16* b0 = Wtb + (size_t)(n0 + srow) * 512 + scol;
  const __bf16* b1 = Wtb + (size_t)(n0 + 64 + srow) * 512 + scol;
  char* sa0 = (char*)As + tid * 16;
  char* sa1 = (char*)As + 4096 + tid * 16;
  char* sb0 = (char*)Bs + tid * 16;
  char* sb1 = (char*)Bs + 4096 + tid * 16;

  int l = tid & 63, w = tid >> 6;
  int lm = l & 15, lq = l >> 4;
  int wm = w >> 1, wn = w & 1;

  ffrag4 acc[4][4] = {};
  for (int u = 0; u < 12; ++u) {
    size_t au = (size_t)u * 100352;   // u * P * D   (elems)
    size_t bu = (size_t)u * 262144;   // u * D * D   (elems)
    for (int d0 = 0; d0 < 512; d0 += 32) {
      __syncthreads();
      async16(a0 + au + d0, sa0);
      async16(a1 + au + d0, sa1);
      async16(b0 + bu + d0, sb0);
      async16(b1 + bu + d0, sb1);
      __syncthreads();
      bfrag8 af[4], bfr[4];
#pragma unroll
      for (int i = 0; i < 4; ++i)
        af[i] = *(const bfrag8*)&As[(wm * 64 + i * 16 + lm) * 32 + lq * 8];
#pragma unroll
      for (int j = 0; j < 4; ++j)
        bfr[j] = *(const bfrag8*)&Bs[(wn * 64 + j * 16 + lm) * 32 + lq * 8];
#pragma unroll
      for (int i = 0; i < 4; ++i)
#pragma unroll
        for (int j = 0; j < 4; ++j)
          acc[i][j] = __builtin_amdgcn_mfma_f32_16x16x32_bf16(af[i], bfr[j], acc[i][j], 0, 0, 0);
    }
  }

#pragma unroll
  for (int i = 0; i < 4; ++i) {
    int mbase = m0 + wm * 64 + i * 16 + lq * 4;
#pragma unroll
    for (int j = 0; j < 4; ++j) {
      int n = n0 + wn * 64 + j * 16 + lm;
      float bj = sbt[n];
#pragma unroll
      for (int r = 0; r < 4; ++r) {
        int mr = mbase + r;
        if (mr < 9408) {
          float v = acc[i][j][r] * (1.f / 12.f) + bj;
          xmid[(size_t)mr * 512 + n] = xin[(size_t)mr * 512 + n] + gelu_exact(v);
        }
      }
    }
  }
}

// ------------- MFMA attention: one block per (b,u,h,t-half) -----------------
// K/V staged ONCE per block, reused across 6 t values (12x less staging than
// per-(t,u) blocks). V^T staged via bf162-pair writes: lanes cover consecutive
// key-pairs -> banks fully spread (<=2-way, free; was 16-way).
// LDS: Ks[208][72] + Vt[64][228] (cols 196..227 zeroed) + 4x P[16][40]
//    = 29952 + 29184 + 5120 = 64256 B -> 2 blocks/CU.
__global__ __launch_bounds__(256) void attn_kernel(
    const __bf16* __restrict__ Q, const __bf16* __restrict__ K,
    const __bf16* __restrict__ V, __bf16* __restrict__ av)
{
  __shared__ __bf16 Ks[208 * 72];
  __shared__ __bf16 Vt[64 * 228];
  __shared__ __bf16 Pball[4 * 16 * 40];

  int bid = blockIdx.x;
  int half = bid & 1;
  int h = (bid >> 1) & 7;
  int r0 = bid >> 4;               // 0..47
  int u = r0 % 12;
  int b = r0 / 12;

  const __bf16* Kp = K + ((size_t)(b * 12 + u) * 196) * 512 + h * 64;
  const __bf16* Vp = V + ((size_t)(b * 12 + u) * 196) * 512 + h * 64;

  // zero Vt pad cols 196..227 (b32 stores)
  for (int idx = threadIdx.x; idx < 64 * 16; idx += 256) {
    int r = idx >> 4;
    int c2 = (idx & 15) * 2 + 196;
    bf16p2 z; z.v[0] = (__bf16)0.f; z.v[1] = (__bf16)0.f;
    *(bf16p2*)&Vt[r * 228 + c2] = z;
  }
  // K rows, vectorized b128
  for (int idx = threadIdx.x; idx < 196 * 8; idx += 256) {
    int r = idx >> 3, c8 = (idx & 7) * 8;
    *(bfrag8*)&Ks[r * 72 + c8] = *(const bfrag8*)&Kp[(size_t)r * 512 + c8];
  }
  // V^T, key-pair bf162 writes (conflict-free: consecutive lanes -> consecutive
  // r2/2 -> distinct banks)
  for (int idx = threadIdx.x; idx < 98 * 8; idx += 256) {
    int r2 = (idx % 98) * 2;
    int c8 = (idx / 98) * 8;
    bfrag8 va = *(const bfrag8*)&Vp[(size_t)r2 * 512 + c8];
    bfrag8 vb = *(const bfrag8*)&Vp[(size_t)(r2 + 1) * 512 + c8];
#pragma unroll
    for (int e = 0; e < 8; ++e) {
      bf16p2 pr; pr.v[0] = va[e]; pr.v[1] = vb[e];
      *(bf16p2*)&Vt[(c8 + e) * 228 + r2] = pr;
    }
  }
  __syncthreads();

  int w = threadIdx.x >> 6, l = threadIdx.x & 63;
  int lm = l & 15, lq = l >> 4;
  __bf16* Pb = Pball + w * (16 * 40);

  for (int tt = 0; tt < 6; ++tt) {
    int t = half * 6 + tt;
    const __bf16* Qp = Q + ((size_t)(b * 12 + t) * 196) * 512 + h * 64;
    __bf16* avp = av + ((size_t)((b * 12 + t) * 12 + u) * 196) * 512 + h * 64;
    int nq = 3 + (((tt & 3) == w) ? 1 : 0);   // wave (tt%4) takes q-tile 12

    for (int qi = 0; qi < nq; ++qi) {
      int qt = (qi < 3) ? (w + qi * 4) : 12;
      int q0 = qt * 16;
      const __bf16* qp = Qp + (size_t)(q0 + lm) * 512 + lq * 8;
      bfrag8 aq0 = *(const bfrag8*)qp;
      bfrag8 aq1 = *(const bfrag8*)(qp + 32);

      ffrag4 S[13];
#pragma unroll
      for (int nt = 0; nt < 13; ++nt) {
        ffrag4 s = {0.f, 0.f, 0.f, 0.f};
        bfrag8 kb0 = *(const bfrag8*)&Ks[(nt * 16 + lm) * 72 + lq * 8];
        bfrag8 kb1 = *(const bfrag8*)&Ks[(nt * 16 + lm) * 72 + 32 + lq * 8];
        s = __builtin_amdgcn_mfma_f32_16x16x32_bf16(aq0, kb0, s, 0, 0, 0);
        s = __builtin_amdgcn_mfma_f32_16x16x32_bf16(aq1, kb1, s, 0, 0, 0);
        S[nt] = s;
      }

#pragma unroll
      for (int nt = 0; nt < 13; ++nt) {
#pragma unroll
        for (int r = 0; r < 4; ++r) {
          float s = S[nt][r] * 0.125f;
          if (nt == 12 && lm >= 4) s = -3.0e38f;
          S[nt][r] = s;
        }
      }

      float sums[4];
#pragma unroll
      for (int r = 0; r < 4; ++r) {
        float mx = -3.0e38f;
#pragma unroll
        for (int nt = 0; nt < 13; ++nt) mx = fmaxf(mx, S[nt][r]);
        mx = fmaxf(mx, __shfl_xor(mx, 1));
        mx = fmaxf(mx, __shfl_xor(mx, 2));
        mx = fmaxf(mx, __shfl_xor(mx, 4));
        mx = fmaxf(mx, __shfl_xor(mx, 8));
        float sum = 0.f;
#pragma unroll
        for (int nt = 0; nt < 13; ++nt) {
          float e = __expf(S[nt][r] - mx);
          S[nt][r] = e;
          sum += e;
        }
        sum += __shfl_xor(sum, 1);
        sum += __shfl_xor(sum, 2);
        sum += __shfl_xor(sum, 4);
        sum += __shfl_xor(sum, 8);
        sums[r] = sum;
      }

      ffrag4 O0 = {0.f, 0.f, 0.f, 0.f}, O1 = O0, O2 = O0, O3 = O0;
      for (int c = 0; c < 7; ++c) {
        int t0 = 2 * c, t1 = 2 * c + 1;
#pragma unroll
        for (int r = 0; r < 4; ++r) {
          int row = lq * 4 + r;
          Pb[row * 40 + lm] = (__bf16)S[t0][r];
          Pb[row * 40 + 16 + lm] = (__bf16)(t1 < 13 ? S[t1][r] : 0.f);
        }
        __threadfence_block();
        bfrag8 pa = *(const bfrag8*)&Pb[lm * 40 + lq * 8];
        bfrag8 v0 = *(const bfrag8*)&Vt[(0 * 16 + lm) * 228 + c * 32 + lq * 8];
        bfrag8 v1 = *(const bfrag8*)&Vt[(1 * 16 + lm) * 228 + c * 32 + lq * 8];
        bfrag8 v2 = *(const bfrag8*)&Vt[(2 * 16 + lm) * 228 + c * 32 + lq * 8];
        bfrag8 v3 = *(const bfrag8*)&Vt[(3 * 16 + lm) * 228 + c * 32 + lq * 8];
        O0 = __builtin_amdgcn_mfma_f32_16x16x32_bf16(pa, v0, O0, 0, 0, 0);
        O1 = __builtin_amdgcn_mfma_f32_16x16x32_bf16(pa, v1, O1, 0, 0, 0);
        O2 = __builtin_amdgcn_mfma_f32_16x16x32_bf16(pa, v2, O2, 0, 0, 0);
        O3 = __builtin_amdgcn_mfma_f32_16x16x32_bf16(pa, v3, O3, 0, 0, 0);
      }

      float inv[4];
#pragma unroll
      for (int r = 0; r < 4; ++r) inv[r] = 1.f / sums[r];

#pragma unroll
      for (int r = 0; r < 4; ++r) {
        int q = q0 + lq * 4 + r;
        if (q < 196) {
          size_t base = (size_t)q * 512 + lm;
          avp[base +  0] = (__bf16)(O0[r] * inv[r]);
          avp[base + 16] = (__bf16)(O1[r] * inv[r]);
          avp[base + 32] = (__bf16)(O2[r] * inv[r]);
          avp[base + 48] = (__bf16)(O3[r] * inv[r]);
        }
      }
    }
  }
}

extern "C" void kernel_launch(void* const* d_in, const int* in_sizes, int n_in,
                              void* d_out, int out_size, void* d_ws, size_t ws_size,
                              hipStream_t stream)
{
  const float* x      = (const float*)d_in[0];
  const float* Wq     = (const float*)d_in[1];
  const float* bq     = (const float*)d_in[2];
  const float* Wk     = (const float*)d_in[3];
  const float* bk     = (const float*)d_in[4];
  const float* Wv     = (const float*)d_in[5];
  const float* bv     = (const float*)d_in[6];
  const float* in_a   = (const float*)d_in[7];
  const float* in_b   = (const float*)d_in[8];
  const float* attn_a = (const float*)d_in[9];
  const float* attn_b = (const float*)d_in[10];
  const float* out_a  = (const float*)d_in[11];
  const float* out_b  = (const float*)d_in[12];
  const float* Wt     = (const float*)d_in[13];
  const float* bt     = (const float*)d_in[14];
  const float* pos    = (const float*)d_in[15];
  const float* W1     = (const float*)d_in[16];
  const float* b1     = (const float*)d_in[17];
  const float* W2     = (const float*)d_in[18];
  const float* b2     = (const float*)d_in[19];

  char* ws = (char*)d_ws;
  const size_t bfb = (size_t)9408 * 512 * 2;       // 9,633,792 B (bf16 MxD)
  __bf16* x2b  = (__bf16*)(ws);
  __bf16* Qb   = (__bf16*)(ws + bfb);
  __bf16* Kb   = (__bf16*)(ws + 2 * bfb);
  __bf16* Vb   = (__bf16*)(ws + 3 * bfb);
  __bf16* av   = (__bf16*)(ws + 4 * bfb);          // 115,605,504 B
  char*   wreg = ws + 4 * bfb + (size_t)115605504; // weights bf16, 9,961,472 B
  __bf16* Wqb  = (__bf16*)(wreg);
  __bf16* Wkb  = (__bf16*)(wreg) + 262144;
  __bf16* Wvb  = (__bf16*)(wreg) + 524288;
  __bf16* W1b  = (__bf16*)(wreg) + 786432;
  __bf16* W2b  = (__bf16*)(wreg) + 1310720;
  __bf16* Wtb  = (__bf16*)(wreg) + 1835008;
  float*  sbt  = (float*)(wreg + 9961472);
  // overlays (stream-ordered lifetimes):
  float*  xmid = (float*)(ws);                     // over x2b+Qb
  __bf16* x3b  = (__bf16*)(ws + 2 * bfb);          // over Kb
  __bf16* hb   = (__bf16*)(ws + 4 * bfb);          // over av
  float*  out  = (float*)d_out;

  conv_w_kernel<<<2432, 256, 0, stream>>>(Wq, Wk, Wv, W1, W2, Wt, (__bf16*)wreg);
  sum_bt_kernel<<<1, 512, 0, stream>>>(bt, sbt);
  norm_f32_to_bf16_kernel<<<9408, 64, 0, stream>>>(x, x2b, in_a, in_b);
  mfma_nt_kernel<<<dim3(12, 74), 256, 0, stream>>>(
      x2b, Wqb, Wkb, Wvb, bq, bk, bv, Qb, Kb, Vb, nullptr, nullptr, 512, 0);
  attn_kernel<<<768, 256, 0, stream>>>(Qb, Kb, Vb, av);
  norm_av_kernel<<<112896, 64, 0, stream>>>((bf16*)av, attn_a, attn_b, pos);
  mfma_tc_kernel<<<dim3(4, 74), 256, 0, stream>>>(av, Wtb, sbt, x, xmid);
  norm_f32_to_bf16_kernel<<<9408, 64, 0, stream>>>(xmid, x3b, out_a, out_b);
  mfma_nt_kernel<<<dim3(8, 74), 256, 0, stream>>>(
      x3b, W1b, nullptr, nullptr, b1, nullptr, nullptr, hb, nullptr, nullptr,
      nullptr, nullptr, 512, 1);
  mfma_nt_kernel<<<dim3(4, 74), 256, 0, stream>>>(
      hb, W2b, nullptr, nullptr, b2, nullptr, nullptr, nullptr, nullptr, nullptr,
      xmid, out, 1024, 2);
}

// Round 5
// 541.427 us; speedup vs baseline: 6.6739x; 1.1722x over previous
//
#include <hip/hip_runtime.h>
#include <hip/hip_bf16.h>

typedef __hip_bfloat16 bf16;

typedef __bf16 bfrag8 __attribute__((ext_vector_type(8)));
typedef __bf16 bfrag4 __attribute__((ext_vector_type(4)));
typedef float  ffrag4 __attribute__((ext_vector_type(4)));
typedef float  ffrag16 __attribute__((ext_vector_type(16)));

// B=4, T=12, P=196, D=512, H=8, DH=64 ; M = B*T*P = 9408
#define EPS 1e-6f

__device__ __forceinline__ float gelu_exact(float v) {
  return 0.5f * v * (1.0f + erff(v * 0.7071067811865475f));
}

__device__ __forceinline__ void async16(const void* g, void* s) {
  __builtin_amdgcn_global_load_lds(
      (const __attribute__((address_space(1))) unsigned int*)g,
      (__attribute__((address_space(3))) unsigned int*)s, 16, 0, 0);
}

struct alignas(16) bf16x8 { bf16 v[8]; };
struct alignas(4)  bf16p2 { __bf16 v[2]; };

// ---------------- weight convert f32 -> bf16, packed region ----------------
__global__ __launch_bounds__(256) void conv_w_kernel(
    const float* __restrict__ Wq, const float* __restrict__ Wk,
    const float* __restrict__ Wv, const float* __restrict__ W1,
    const float* __restrict__ W2, const float* __restrict__ Wt,
    __bf16* __restrict__ dst)
{
  size_t e = ((size_t)blockIdx.x * 256 + threadIdx.x) * 8;
  const float* src; size_t off;
  if      (e <  262144) { src = Wq; off = e; }
  else if (e <  524288) { src = Wk; off = e -  262144; }
  else if (e <  786432) { src = Wv; off = e -  524288; }
  else if (e < 1310720) { src = W1; off = e -  786432; }
  else if (e < 1835008) { src = W2; off = e - 1310720; }
  else if (e < 4980736) { src = Wt; off = e - 1835008; }
  else return;
  float4 f0 = *(const float4*)(src + off);
  float4 f1 = *(const float4*)(src + off + 4);
  bfrag8 o;
  o[0] = (__bf16)f0.x; o[1] = (__bf16)f0.y; o[2] = (__bf16)f0.z; o[3] = (__bf16)f0.w;
  o[4] = (__bf16)f1.x; o[5] = (__bf16)f1.y; o[6] = (__bf16)f1.z; o[7] = (__bf16)f1.w;
  *(bfrag8*)(dst + e) = o;
}

__global__ __launch_bounds__(512) void sum_bt_kernel(
    const float* __restrict__ bt, float* __restrict__ sbt)
{
  int n = threadIdx.x;
  float s = 0.f;
#pragma unroll
  for (int u = 0; u < 12; ++u) s += bt[u * 512 + n];
  sbt[n] = s;
}

// ------------- LayerNorm f32 -> bf16, one 64-thread block per row of 512 ----
__global__ __launch_bounds__(64) void norm_f32_to_bf16_kernel(
    const float* __restrict__ in, __bf16* __restrict__ out,
    const float* __restrict__ alpha, const float* __restrict__ beta)
{
  size_t row = blockIdx.x;
  int l = threadIdx.x;
  const float* r = in + row * 512 + l * 8;
  float4 v0 = *(const float4*)(r);
  float4 v1 = *(const float4*)(r + 4);
  float f[8] = {v0.x, v0.y, v0.z, v0.w, v1.x, v1.y, v1.z, v1.w};
  float s = 0.f, ss = 0.f;
#pragma unroll
  for (int q = 0; q < 8; ++q) { s += f[q]; ss += f[q] * f[q]; }
#pragma unroll
  for (int off = 32; off; off >>= 1) { s += __shfl_xor(s, off); ss += __shfl_xor(ss, off); }
  float mu = s * (1.f / 512.f);
  float var = fmaxf((ss - 512.f * mu * mu) * (1.f / 511.f), 0.f);
  float inv = 1.f / (sqrtf(var) + EPS);
  const float* al = alpha + l * 8;
  const float* be = beta + l * 8;
  float4 a0 = *(const float4*)al, a1 = *(const float4*)(al + 4);
  float4 b0 = *(const float4*)be, b1 = *(const float4*)(be + 4);
  float aa[8] = {a0.x, a0.y, a0.z, a0.w, a1.x, a1.y, a1.z, a1.w};
  float bb[8] = {b0.x, b0.y, b0.z, b0.w, b1.x, b1.y, b1.z, b1.w};
  bfrag8 o;
#pragma unroll
  for (int q = 0; q < 8; ++q) o[q] = (__bf16)(aa[q] * (f[q] - mu) * inv + bb[q]);
  *(bfrag8*)(out + row * 512 + l * 8) = o;
}

// ------------- LayerNorm bf16 in-place + pos add (x2p = norm(av)+pos) -------
__global__ __launch_bounds__(64) void norm_av_kernel(
    bf16* __restrict__ av, const float* __restrict__ alpha,
    const float* __restrict__ beta, const float* __restrict__ pos)
{
  size_t row = blockIdx.x;          // [0, B*T*T*P)
  int l = threadIdx.x;
  bf16* r = av + row * 512 + (size_t)l * 8;
  bf16x8 ib = *(const bf16x8*)r;
  float f[8];
#pragma unroll
  for (int q = 0; q < 8; ++q) f[q] = __bfloat162float(ib.v[q]);
  float s = 0.f, ss = 0.f;
#pragma unroll
  for (int q = 0; q < 8; ++q) { s += f[q]; ss += f[q] * f[q]; }
#pragma unroll
  for (int off = 32; off; off >>= 1) { s += __shfl_xor(s, off); ss += __shfl_xor(ss, off); }
  float mu = s * (1.f / 512.f);
  float var = fmaxf((ss - 512.f * mu * mu) * (1.f / 511.f), 0.f);
  float inv = 1.f / (sqrtf(var) + EPS);
  size_t prow = row % 28224;        // T*T*P  (pos broadcasts over batch)
  const float* pr = pos + prow * 512 + l * 8;
  float4 p0 = *(const float4*)pr, p1 = *(const float4*)(pr + 4);
  const float* al = alpha + l * 8;
  const float* be = beta + l * 8;
  float4 a0 = *(const float4*)al, a1 = *(const float4*)(al + 4);
  float4 b0 = *(const float4*)be, b1 = *(const float4*)(be + 4);
  float pa[8] = {p0.x, p0.y, p0.z, p0.w, p1.x, p1.y, p1.z, p1.w};
  float aa[8] = {a0.x, a0.y, a0.z, a0.w, a1.x, a1.y, a1.z, a1.w};
  float bb[8] = {b0.x, b0.y, b0.z, b0.w, b1.x, b1.y, b1.z, b1.w};
  bf16x8 ob;
#pragma unroll
  for (int q = 0; q < 8; ++q)
    ob.v[q] = __float2bfloat16(aa[q] * (f[q] - mu) * inv + bb[q] + pa[q]);
  *(bf16x8*)r = ob;
}

// ------------- MFMA NT GEMM, 128x128 tile, BK=32, global_load_lds staging ---
// mode 0: fused QKV (N=1536, B/bias/out selected by n-block), out bf16 +bias
// mode 1: MLP1 (N=1024), out bf16 = gelu(acc+bias)
// mode 2: MLP2 (N=512),  out f32 = res + gelu(acc+bias)
__global__ __launch_bounds__(256) void mfma_nt_kernel(
    const __bf16* __restrict__ A,
    const __bf16* __restrict__ Bq, const __bf16* __restrict__ Bk,
    const __bf16* __restrict__ Bv,
    const float* __restrict__ bq, const float* __restrict__ bk,
    const float* __restrict__ bv,
    __bf16* __restrict__ oq, __bf16* __restrict__ ok, __bf16* __restrict__ ov,
    const float* __restrict__ res, float* __restrict__ fout,
    int K, int mode)
{
  __shared__ __bf16 As[128 * 32];
  __shared__ __bf16 Bs[128 * 32];
  int tid = threadIdx.x;
  int m0 = blockIdx.y * 128;
  int n0g = blockIdx.x * 128;

  const __bf16* Bsel; const float* biassel; __bf16* osel; int ncol0;
  if (mode == 0) {
    int sel = n0g >> 9;
    Bsel = sel == 0 ? Bq : (sel == 1 ? Bk : Bv);
    biassel = sel == 0 ? bq : (sel == 1 ? bk : bv);
    osel = sel == 0 ? oq : (sel == 1 ? ok : ov);
    ncol0 = n0g & 511;
  } else {
    Bsel = Bq; biassel = bq; osel = oq; ncol0 = n0g;
  }

  int srow = tid >> 2, scol = (tid & 3) * 8;
  int r0 = m0 + srow;      if (r0 > 9407) r0 = 9407;
  int r1 = m0 + 64 + srow; if (r1 > 9407) r1 = 9407;
  const __bf16* a0 = A + (size_t)r0 * K + scol;
  const __bf16* a1 = A + (size_t)r1 * K + scol;
  const __bf16* b0 = Bsel + (size_t)(ncol0 + srow) * K + scol;
  const __bf16* b1 = Bsel + (size_t)(ncol0 + 64 + srow) * K + scol;
  char* sa0 = (char*)As + tid * 16;
  char* sa1 = (char*)As + 4096 + tid * 16;
  char* sb0 = (char*)Bs + tid * 16;
  char* sb1 = (char*)Bs + 4096 + tid * 16;

  int l = tid & 63, w = tid >> 6;
  int lm = l & 15, lq = l >> 4;
  int wm = w >> 1, wn = w & 1;

  ffrag4 acc[4][4] = {};
  for (int k0 = 0; k0 < K; k0 += 32) {
    __syncthreads();
    async16(a0 + k0, sa0);
    async16(a1 + k0, sa1);
    async16(b0 + k0, sb0);
    async16(b1 + k0, sb1);
    __syncthreads();
    bfrag8 af[4], bfr[4];
#pragma unroll
    for (int i = 0; i < 4; ++i)
      af[i] = *(const bfrag8*)&As[(wm * 64 + i * 16 + lm) * 32 + lq * 8];
#pragma unroll
    for (int j = 0; j < 4; ++j)
      bfr[j] = *(const bfrag8*)&Bs[(wn * 64 + j * 16 + lm) * 32 + lq * 8];
#pragma unroll
    for (int i = 0; i < 4; ++i)
#pragma unroll
      for (int j = 0; j < 4; ++j)
        acc[i][j] = __builtin_amdgcn_mfma_f32_16x16x32_bf16(af[i], bfr[j], acc[i][j], 0, 0, 0);
  }

#pragma unroll
  for (int i = 0; i < 4; ++i) {
    int mbase = m0 + wm * 64 + i * 16 + lq * 4;
#pragma unroll
    for (int j = 0; j < 4; ++j) {
      int n = ncol0 + wn * 64 + j * 16 + lm;
      float bj = biassel[n];
#pragma unroll
      for (int r = 0; r < 4; ++r) {
        int mr = mbase + r;
        if (mr < 9408) {
          float v = acc[i][j][r] + bj;
          if (mode == 0)      osel[(size_t)mr * 512 + n] = (__bf16)v;
          else if (mode == 1) osel[(size_t)mr * 1024 + n] = (__bf16)gelu_exact(v);
          else                fout[(size_t)mr * 512 + n] =
                                res[(size_t)mr * 512 + n] + gelu_exact(v);
        }
      }
    }
  }
}

// ------- temporal mixing via MFMA: 64x128 tile (588 blocks, better occupancy)
__global__ __launch_bounds__(256) void mfma_tc_kernel(
    const __bf16* __restrict__ X2p, const __bf16* __restrict__ Wtb,
    const float* __restrict__ sbt, const float* __restrict__ xin,
    float* __restrict__ xmid)
{
  __shared__ __bf16 As[64 * 32];
  __shared__ __bf16 Bs[128 * 32];
  int tid = threadIdx.x;
  int m0 = blockIdx.y * 64;        // 147 m-blocks, exact
  int n0 = blockIdx.x * 128;       // 4 n-blocks

  int srow = tid >> 2, scol = (tid & 3) * 8;
  int r0 = m0 + srow;
  int btq0 = r0 / 196, p0 = r0 - btq0 * 196;
  const __bf16* a0 = X2p + (size_t)btq0 * 1204224 + (size_t)p0 * 512 + scol;
  const __bf16* b0 = Wtb + (size_t)(n0 + srow) * 512 + scol;
  const __bf16* b1 = Wtb + (size_t)(n0 + 64 + srow) * 512 + scol;
  char* sa0 = (char*)As + tid * 16;
  char* sb0 = (char*)Bs + tid * 16;
  char* sb1 = (char*)Bs + 4096 + tid * 16;

  int l = tid & 63, w = tid >> 6;
  int lm = l & 15, lq = l >> 4;
  int wm = w >> 1, wn = w & 1;

  ffrag4 acc[2][4] = {};
  for (int u = 0; u < 12; ++u) {
    size_t au = (size_t)u * 100352;   // u * P * D
    size_t bu = (size_t)u * 262144;   // u * D * D
    for (int d0 = 0; d0 < 512; d0 += 32) {
      __syncthreads();
      async16(a0 + au + d0, sa0);
      async16(b0 + bu + d0, sb0);
      async16(b1 + bu + d0, sb1);
      __syncthreads();
      bfrag8 af[2], bfr[4];
#pragma unroll
      for (int i = 0; i < 2; ++i)
        af[i] = *(const bfrag8*)&As[(wm * 32 + i * 16 + lm) * 32 + lq * 8];
#pragma unroll
      for (int j = 0; j < 4; ++j)
        bfr[j] = *(const bfrag8*)&Bs[(wn * 64 + j * 16 + lm) * 32 + lq * 8];
#pragma unroll
      for (int i = 0; i < 2; ++i)
#pragma unroll
        for (int j = 0; j < 4; ++j)
          acc[i][j] = __builtin_amdgcn_mfma_f32_16x16x32_bf16(af[i], bfr[j], acc[i][j], 0, 0, 0);
    }
  }

#pragma unroll
  for (int i = 0; i < 2; ++i) {
    int mbase = m0 + wm * 32 + i * 16 + lq * 4;
#pragma unroll
    for (int j = 0; j < 4; ++j) {
      int n = n0 + wn * 64 + j * 16 + lm;
      float bj = sbt[n];
#pragma unroll
      for (int r = 0; r < 4; ++r) {
        int mr = mbase + r;
        float v = acc[i][j][r] * (1.f / 12.f) + bj;
        xmid[(size_t)mr * 512 + n] = xin[(size_t)mr * 512 + n] + gelu_exact(v);
      }
    }
  }
}

// ------------- MFMA attention v2: 32x32x16, S^T route, no-max softmax -------
// One block (8 waves, 512 thr) per (b,u,h,t-half). K/V staged once.
// S^T = K·Q^T: A=K (LDS, swizzled), B=Q (regs). C-layout: col=query (lane&31),
// row=key ((reg&3)+8*(reg>>2)+4*(lane>>5)). Softmax denominators: per-lane
// adds + one shfl_xor(32). P^T written per 16-key chunk to per-wave Pb[32][20]
// (full-wave b16 writes), read back as A-frags (2xb64) for PV 32x32x16.
// LDS: Ks[196][64] swizzled (25088) + Vt[64][208] pad-zeroed (26624)
//      + 8 x Pb[32][20] (12800) = 64512 B -> 2 blocks/CU, 16 waves/CU.
__global__ __launch_bounds__(512, 4) void attn_kernel(
    const __bf16* __restrict__ Q, const __bf16* __restrict__ K,
    const __bf16* __restrict__ V, __bf16* __restrict__ av)
{
  __shared__ __bf16 Ks[196 * 64];
  __shared__ __bf16 Vt[64 * 208];
  __shared__ __bf16 Pball[8 * 32 * 20];

  int bid = blockIdx.x;
  int half = bid & 1;
  int h = (bid >> 1) & 7;
  int r0 = bid >> 4;               // 0..47
  int u = r0 % 12;
  int b = r0 / 12;

  const __bf16* Kp = K + ((size_t)(b * 12 + u) * 196) * 512 + h * 64;
  const __bf16* Vp = V + ((size_t)(b * 12 + u) * 196) * 512 + h * 64;

  // stage K, group-swizzled: row r group g stored at g^(r&7)
  for (int idx = threadIdx.x; idx < 196 * 8; idx += 512) {
    int r = idx >> 3, g = idx & 7;
    *(bfrag8*)&Ks[r * 64 + ((g ^ (r & 7)) * 8)] =
        *(const bfrag8*)&Kp[(size_t)r * 512 + g * 8];
  }
  // zero Vt pad cols 196..207 (multiplied by P=0, but must be non-NaN)
  for (int idx = threadIdx.x; idx < 64 * 6; idx += 512) {
    int r = idx / 6, c2 = 196 + (idx % 6) * 2;
    bf16p2 z; z.v[0] = (__bf16)0.f; z.v[1] = (__bf16)0.f;
    *(bf16p2*)&Vt[r * 208 + c2] = z;
  }
  // stage V^T via key-pair b32 writes (bank-spread)
  for (int idx = threadIdx.x; idx < 98 * 8; idx += 512) {
    int r2 = (idx % 98) * 2, c8 = (idx / 98) * 8;
    bfrag8 va = *(const bfrag8*)&Vp[(size_t)r2 * 512 + c8];
    bfrag8 vb = *(const bfrag8*)&Vp[(size_t)(r2 + 1) * 512 + c8];
#pragma unroll
    for (int e = 0; e < 8; ++e) {
      bf16p2 pr; pr.v[0] = va[e]; pr.v[1] = vb[e];
      *(bf16p2*)&Vt[(c8 + e) * 208 + r2] = pr;
    }
  }
  __syncthreads();

  int w = threadIdx.x >> 6, l = threadIdx.x & 63;
  int l5 = l >> 5, c = l & 31;
  __bf16* Pb = Pball + w * (32 * 20);

  // 42 units = 6 t x 7 q-tiles, distributed over 8 waves
  for (int unit = w; unit < 42; unit += 8) {
    int t = unit / 7, qt = unit - t * 7;
    int tq = half * 6 + t;
    const __bf16* Qp = Q + ((size_t)(b * 12 + tq) * 196) * 512 + h * 64;
    __bf16* avp = av + ((size_t)((b * 12 + tq) * 12 + u) * 196) * 512 + h * 64;
    int q0 = qt * 32;

    // Q B-frags: lane -> query q0+c, dh chunk kc*16 + l5*8
    const __bf16* qp = Qp + (size_t)(q0 + c) * 512 + l5 * 8;
    bfrag8 qf[4];
    qf[0] = *(const bfrag8*)(qp);
    qf[1] = *(const bfrag8*)(qp + 16);
    qf[2] = *(const bfrag8*)(qp + 32);
    qf[3] = *(const bfrag8*)(qp + 48);

    ffrag16 O0, O1;
#pragma unroll
    for (int g = 0; g < 16; ++g) { O0[g] = 0.f; O1[g] = 0.f; }
    float sumacc = 0.f;

    for (int nt = 0; nt < 7; ++nt) {
      int key = nt * 32 + c; if (key > 195) key = 195;
      const __bf16* kbase = &Ks[key * 64];
      int kx = key & 7;

      ffrag16 s;
#pragma unroll
      for (int g = 0; g < 16; ++g) s[g] = 0.f;
#pragma unroll
      for (int kc = 0; kc < 4; ++kc) {
        bfrag8 kf = *(const bfrag8*)&kbase[(((kc * 2 + l5) ^ kx) * 8)];
        s = __builtin_amdgcn_mfma_f32_32x32x16_bf16(kf, qf[kc], s, 0, 0, 0);
      }

      // p = exp(s/8), mask pad keys (tile 6 rows >= 4 i.e. key >= 196)
#pragma unroll
      for (int g = 0; g < 16; ++g) {
        float e = __expf(s[g] * 0.125f);
        bool keep = (nt < 6) || ((g < 4) && (l5 == 0));
        e = keep ? e : 0.f;
        s[g] = e;
        sumacc += e;
      }

      // PV per 16-key sub-chunk
#pragma unroll
      for (int sub = 0; sub < 2; ++sub) {
        if (nt == 6 && sub == 1) break;
#pragma unroll
        for (int g = 0; g < 8; ++g) {
          int gg = sub * 8 + g;
          int k16 = (gg & 3) + 8 * ((gg >> 2) & 1) + 4 * l5;
          Pb[c * 20 + k16] = (__bf16)s[gg];
        }
        __threadfence_block();
        int ch = nt * 2 + sub;
        bfrag4 plo = *(const bfrag4*)&Pb[c * 20 + l5 * 8];
        bfrag4 phi = *(const bfrag4*)&Pb[c * 20 + l5 * 8 + 4];
        bfrag8 pa = __builtin_shufflevector(plo, phi, 0, 1, 2, 3, 4, 5, 6, 7);
        bfrag8 v0 = *(const bfrag8*)&Vt[(size_t)(c     ) * 208 + ch * 16 + l5 * 8];
        bfrag8 v1 = *(const bfrag8*)&Vt[(size_t)(c + 32) * 208 + ch * 16 + l5 * 8];
        O0 = __builtin_amdgcn_mfma_f32_32x32x16_bf16(pa, v0, O0, 0, 0, 0);
        O1 = __builtin_amdgcn_mfma_f32_32x32x16_bf16(pa, v1, O1, 0, 0, 0);
      }
    }

    // denominators: lane c holds partial sum for query q0+c
    float stot = sumacc + __shfl_xor(sumacc, 32);

#pragma unroll
    for (int g = 0; g < 16; ++g) {
      int row = (g & 3) + 8 * (g >> 2) + 4 * l5;
      float sq = __shfl(stot, row);
      float iv = __builtin_amdgcn_rcpf(sq);
      int q = q0 + row;
      if (q < 196) {
        size_t base = (size_t)q * 512 + c;
        avp[base]      = (__bf16)(O0[g] * iv);
        avp[base + 32] = (__bf16)(O1[g] * iv);
      }
    }
  }
}

extern "C" void kernel_launch(void* const* d_in, const int* in_sizes, int n_in,
                              void* d_out, int out_size, void* d_ws, size_t ws_size,
                              hipStream_t stream)
{
  const float* x      = (const float*)d_in[0];
  const float* Wq     = (const float*)d_in[1];
  const float* bq     = (const float*)d_in[2];
  const float* Wk     = (const float*)d_in[3];
  const float* bk     = (const float*)d_in[4];
  const float* Wv     = (const float*)d_in[5];
  const float* bv     = (const float*)d_in[6];
  const float* in_a   = (const float*)d_in[7];
  const float* in_b   = (const float*)d_in[8];
  const float* attn_a = (const float*)d_in[9];
  const float* attn_b = (const float*)d_in[10];
  const float* out_a  = (const float*)d_in[11];
  const float* out_b  = (const float*)d_in[12];
  const float* Wt     = (const float*)d_in[13];
  const float* bt     = (const float*)d_in[14];
  const float* pos    = (const float*)d_in[15];
  const float* W1     = (const float*)d_in[16];
  const float* b1     = (const float*)d_in[17];
  const float* W2     = (const float*)d_in[18];
  const float* b2     = (const float*)d_in[19];

  char* ws = (char*)d_ws;
  const size_t bfb = (size_t)9408 * 512 * 2;       // 9,633,792 B (bf16 MxD)
  __bf16* x2b  = (__bf16*)(ws);
  __bf16* Qb   = (__bf16*)(ws + bfb);
  __bf16* Kb   = (__bf16*)(ws + 2 * bfb);
  __bf16* Vb   = (__bf16*)(ws + 3 * bfb);
  __bf16* av   = (__bf16*)(ws + 4 * bfb);          // 115,605,504 B
  char*   wreg = ws + 4 * bfb + (size_t)115605504; // weights bf16, 9,961,472 B
  __bf16* Wqb  = (__bf16*)(wreg);
  __bf16* Wkb  = (__bf16*)(wreg) + 262144;
  __bf16* Wvb  = (__bf16*)(wreg) + 524288;
  __bf16* W1b  = (__bf16*)(wreg) + 786432;
  __bf16* W2b  = (__bf16*)(wreg) + 1310720;
  __bf16* Wtb  = (__bf16*)(wreg) + 1835008;
  float*  sbt  = (float*)(wreg + 9961472);
  // overlays (stream-ordered lifetimes):
  float*  xmid = (float*)(ws);                     // over x2b+Qb
  __bf16* x3b  = (__bf16*)(ws + 2 * bfb);          // over Kb
  __bf16* hb   = (__bf16*)(ws + 4 * bfb);          // over av
  float*  out  = (float*)d_out;

  conv_w_kernel<<<2432, 256, 0, stream>>>(Wq, Wk, Wv, W1, W2, Wt, (__bf16*)wreg);
  sum_bt_kernel<<<1, 512, 0, stream>>>(bt, sbt);
  norm_f32_to_bf16_kernel<<<9408, 64, 0, stream>>>(x, x2b, in_a, in_b);
  mfma_nt_kernel<<<dim3(12, 74), 256, 0, stream>>>(
      x2b, Wqb, Wkb, Wvb, bq, bk, bv, Qb, Kb, Vb, nullptr, nullptr, 512, 0);
  attn_kernel<<<768, 512, 0, stream>>>(Qb, Kb, Vb, av);
  norm_av_kernel<<<112896, 64, 0, stream>>>((bf16*)av, attn_a, attn_b, pos);
  mfma_tc_kernel<<<dim3(4, 147), 256, 0, stream>>>(av, Wtb, sbt, x, xmid);
  norm_f32_to_bf16_kernel<<<9408, 64, 0, stream>>>(xmid, x3b, out_a, out_b);
  mfma_nt_kernel<<<dim3(8, 74), 256, 0, stream>>>(
      x3b, W1b, nullptr, nullptr, b1, nullptr, nullptr, hb, nullptr, nullptr,
      nullptr, nullptr, 512, 1);
  mfma_nt_kernel<<<dim3(4, 74), 256, 0, stream>>>(
      hb, W2b, nullptr, nullptr, b2, nullptr, nullptr, nullptr, nullptr, nullptr,
      xmid, out, 1024, 2);
}

// Round 8
// 529.756 us; speedup vs baseline: 6.8209x; 1.0220x over previous
//
#include <hip/hip_runtime.h>
#include <hip/hip_bf16.h>

typedef __hip_bfloat16 bf16;

typedef __bf16 bfrag8 __attribute__((ext_vector_type(8)));
typedef __bf16 bfrag4 __attribute__((ext_vector_type(4)));
typedef float  ffrag4 __attribute__((ext_vector_type(4)));
typedef float  ffrag16 __attribute__((ext_vector_type(16)));

// B=4, T=12, P=196, D=512, H=8, DH=64 ; M = B*T*P = 9408 = 147*64
#define EPS 1e-6f

__device__ __forceinline__ float gelu_exact(float v) {
  return 0.5f * v * (1.0f + erff(v * 0.7071067811865475f));
}

__device__ __forceinline__ void async16(const void* g, void* s) {
  __builtin_amdgcn_global_load_lds(
      (const __attribute__((address_space(1))) unsigned int*)g,
      (__attribute__((address_space(3))) unsigned int*)s, 16, 0, 0);
}

struct alignas(16) bf16x8 { bf16 v[8]; };
struct alignas(4)  bf16p2 { __bf16 v[2]; };

// ---------------- zero the split-K accumulator (graph-capture-safe) ---------
__global__ __launch_bounds__(256) void zero_acc_kernel(float* __restrict__ p) {
  size_t i = ((size_t)blockIdx.x * 256 + threadIdx.x) * 4;
  *(float4*)(p + i) = make_float4(0.f, 0.f, 0.f, 0.f);
}

// ---------------- weight convert f32 -> bf16, packed region ----------------
__global__ __launch_bounds__(256) void conv_w_kernel(
    const float* __restrict__ Wq, const float* __restrict__ Wk,
    const float* __restrict__ Wv, const float* __restrict__ W1,
    const float* __restrict__ W2, const float* __restrict__ Wt,
    __bf16* __restrict__ dst)
{
  size_t e = ((size_t)blockIdx.x * 256 + threadIdx.x) * 8;
  const float* src; size_t off;
  if      (e <  262144) { src = Wq; off = e; }
  else if (e <  524288) { src = Wk; off = e -  262144; }
  else if (e <  786432) { src = Wv; off = e -  524288; }
  else if (e < 1310720) { src = W1; off = e -  786432; }
  else if (e < 1835008) { src = W2; off = e - 1310720; }
  else if (e < 4980736) { src = Wt; off = e - 1835008; }
  else return;
  float4 f0 = *(const float4*)(src + off);
  float4 f1 = *(const float4*)(src + off + 4);
  bfrag8 o;
  o[0] = (__bf16)f0.x; o[1] = (__bf16)f0.y; o[2] = (__bf16)f0.z; o[3] = (__bf16)f0.w;
  o[4] = (__bf16)f1.x; o[5] = (__bf16)f1.y; o[6] = (__bf16)f1.z; o[7] = (__bf16)f1.w;
  *(bfrag8*)(dst + e) = o;
}

__global__ __launch_bounds__(512) void sum_bt_kernel(
    const float* __restrict__ bt, float* __restrict__ sbt)
{
  int n = threadIdx.x;
  float s = 0.f;
#pragma unroll
  for (int u = 0; u < 12; ++u) s += bt[u * 512 + n];
  sbt[n] = s;
}

// ------------- LayerNorm f32 -> bf16, one 64-thread block per row of 512 ----
__global__ __launch_bounds__(64) void norm_f32_to_bf16_kernel(
    const float* __restrict__ in, __bf16* __restrict__ out,
    const float* __restrict__ alpha, const float* __restrict__ beta)
{
  size_t row = blockIdx.x;
  int l = threadIdx.x;
  const float* r = in + row * 512 + l * 8;
  float4 v0 = *(const float4*)(r);
  float4 v1 = *(const float4*)(r + 4);
  float f[8] = {v0.x, v0.y, v0.z, v0.w, v1.x, v1.y, v1.z, v1.w};
  float s = 0.f, ss = 0.f;
#pragma unroll
  for (int q = 0; q < 8; ++q) { s += f[q]; ss += f[q] * f[q]; }
#pragma unroll
  for (int off = 32; off; off >>= 1) { s += __shfl_xor(s, off); ss += __shfl_xor(ss, off); }
  float mu = s * (1.f / 512.f);
  float var = fmaxf((ss - 512.f * mu * mu) * (1.f / 511.f), 0.f);
  float inv = 1.f / (sqrtf(var) + EPS);
  const float* al = alpha + l * 8;
  const float* be = beta + l * 8;
  float4 a0 = *(const float4*)al, a1 = *(const float4*)(al + 4);
  float4 b0 = *(const float4*)be, b1 = *(const float4*)(be + 4);
  float aa[8] = {a0.x, a0.y, a0.z, a0.w, a1.x, a1.y, a1.z, a1.w};
  float bb[8] = {b0.x, b0.y, b0.z, b0.w, b1.x, b1.y, b1.z, b1.w};
  bfrag8 o;
#pragma unroll
  for (int q = 0; q < 8; ++q) o[q] = (__bf16)(aa[q] * (f[q] - mu) * inv + bb[q]);
  *(bfrag8*)(out + row * 512 + l * 8) = o;
}

// ------------- LayerNorm bf16 in-place + pos add (x2p = norm(av)+pos) -------
__global__ __launch_bounds__(64) void norm_av_kernel(
    bf16* __restrict__ av, const float* __restrict__ alpha,
    const float* __restrict__ beta, const float* __restrict__ pos)
{
  size_t row = blockIdx.x;          // [0, B*T*T*P)
  int l = threadIdx.x;
  bf16* r = av + row * 512 + (size_t)l * 8;
  bf16x8 ib = *(const bf16x8*)r;
  float f[8];
#pragma unroll
  for (int q = 0; q < 8; ++q) f[q] = __bfloat162float(ib.v[q]);
  float s = 0.f, ss = 0.f;
#pragma unroll
  for (int q = 0; q < 8; ++q) { s += f[q]; ss += f[q] * f[q]; }
#pragma unroll
  for (int off = 32; off; off >>= 1) { s += __shfl_xor(s, off); ss += __shfl_xor(ss, off); }
  float mu = s * (1.f / 512.f);
  float var = fmaxf((ss - 512.f * mu * mu) * (1.f / 511.f), 0.f);
  float inv = 1.f / (sqrtf(var) + EPS);
  size_t prow = row % 28224;        // T*T*P  (pos broadcasts over batch)
  const float* pr = pos + prow * 512 + l * 8;
  float4 p0 = *(const float4*)pr, p1 = *(const float4*)(pr + 4);
  const float* al = alpha + l * 8;
  const float* be = beta + l * 8;
  float4 a0 = *(const float4*)al, a1 = *(const float4*)(al + 4);
  float4 b0 = *(const float4*)be, b1 = *(const float4*)(be + 4);
  float pa[8] = {p0.x, p0.y, p0.z, p0.w, p1.x, p1.y, p1.z, p1.w};
  float aa[8] = {a0.x, a0.y, a0.z, a0.w, a1.x, a1.y, a1.z, a1.w};
  float bb[8] = {b0.x, b0.y, b0.z, b0.w, b1.x, b1.y, b1.z, b1.w};
  bf16x8 ob;
#pragma unroll
  for (int q = 0; q < 8; ++q)
    ob.v[q] = __float2bfloat16(aa[q] * (f[q] - mu) * inv + bb[q] + pa[q]);
  *(bf16x8*)r = ob;
}

// ------------- MFMA NT GEMM, 64x128 tile, BK=32, global_load_lds staging ----
// mode 0: fused QKV (N=1536, B/bias/out selected by n-block), out bf16 +bias
// mode 1: MLP1 (N=1024), out bf16 = gelu(acc+bias)
// mode 2: MLP2 (N=512),  out f32 = res + gelu(acc+bias)
__global__ __launch_bounds__(256) void mfma_nt_kernel(
    const __bf16* __restrict__ A,
    const __bf16* __restrict__ Bq, const __bf16* __restrict__ Bk,
    const __bf16* __restrict__ Bv,
    const float* __restrict__ bq, const float* __restrict__ bk,
    const float* __restrict__ bv,
    __bf16* __restrict__ oq, __bf16* __restrict__ ok, __bf16* __restrict__ ov,
    const float* __restrict__ res, float* __restrict__ fout,
    int K, int mode)
{
  __shared__ __bf16 As[64 * 32];
  __shared__ __bf16 Bs[128 * 32];
  int tid = threadIdx.x;
  int m0 = blockIdx.y * 64;
  int n0g = blockIdx.x * 128;

  const __bf16* Bsel; const float* biassel; __bf16* osel; int ncol0;
  if (mode == 0) {
    int sel = n0g >> 9;
    Bsel = sel == 0 ? Bq : (sel == 1 ? Bk : Bv);
    biassel = sel == 0 ? bq : (sel == 1 ? bk : bv);
    osel = sel == 0 ? oq : (sel == 1 ? ok : ov);
    ncol0 = n0g & 511;
  } else {
    Bsel = Bq; biassel = bq; osel = oq; ncol0 = n0g;
  }

  int srow = tid >> 2, scol = (tid & 3) * 8;
  const __bf16* a0 = A + (size_t)(m0 + srow) * K + scol;
  const __bf16* b0 = Bsel + (size_t)(ncol0 + srow) * K + scol;
  const __bf16* b1 = Bsel + (size_t)(ncol0 + 64 + srow) * K + scol;
  char* sa0 = (char*)As + tid * 16;
  char* sb0 = (char*)Bs + tid * 16;
  char* sb1 = (char*)Bs + 4096 + tid * 16;

  int l = tid & 63, w = tid >> 6;
  int lm = l & 15, lq = l >> 4;
  int wm = w >> 1, wn = w & 1;

  ffrag4 acc[2][4] = {};
  for (int k0 = 0; k0 < K; k0 += 32) {
    __syncthreads();
    async16(a0 + k0, sa0);
    async16(b0 + k0, sb0);
    async16(b1 + k0, sb1);
    __syncthreads();
    bfrag8 af[2], bfr[4];
#pragma unroll
    for (int i = 0; i < 2; ++i)
      af[i] = *(const bfrag8*)&As[(wm * 32 + i * 16 + lm) * 32 + lq * 8];
#pragma unroll
    for (int j = 0; j < 4; ++j)
      bfr[j] = *(const bfrag8*)&Bs[(wn * 64 + j * 16 + lm) * 32 + lq * 8];
#pragma unroll
    for (int i = 0; i < 2; ++i)
#pragma unroll
      for (int j = 0; j < 4; ++j)
        acc[i][j] = __builtin_amdgcn_mfma_f32_16x16x32_bf16(af[i], bfr[j], acc[i][j], 0, 0, 0);
  }

#pragma unroll
  for (int i = 0; i < 2; ++i) {
    int mbase = m0 + wm * 32 + i * 16 + lq * 4;
#pragma unroll
    for (int j = 0; j < 4; ++j) {
      int n = ncol0 + wn * 64 + j * 16 + lm;
      float bj = biassel[n];
#pragma unroll
      for (int r = 0; r < 4; ++r) {
        int mr = mbase + r;
        float v = acc[i][j][r] + bj;
        if (mode == 0)      osel[(size_t)mr * 512 + n] = (__bf16)v;
        else if (mode == 1) osel[(size_t)mr * 1024 + n] = (__bf16)gelu_exact(v);
        else                fout[(size_t)mr * 512 + n] =
                              res[(size_t)mr * 512 + n] + gelu_exact(v);
      }
    }
  }
}

// ------- temporal mixing, split-K over u: grid (4,147,4); each block does
// 3 u's and atomically accumulates its f32 partial into acc (pre-zeroed).
__global__ __launch_bounds__(256) void mfma_tc_kernel(
    const __bf16* __restrict__ X2p, const __bf16* __restrict__ Wtb,
    float* __restrict__ accb)
{
  __shared__ __bf16 As[64 * 32];
  __shared__ __bf16 Bs[128 * 32];
  int tid = threadIdx.x;
  int m0 = blockIdx.y * 64;        // 147 m-blocks, exact
  int n0 = blockIdx.x * 128;       // 4 n-blocks
  int ug = blockIdx.z * 3;         // u-group: 3 u's per block

  int srow = tid >> 2, scol = (tid & 3) * 8;
  int r0 = m0 + srow;
  int btq0 = r0 / 196, p0 = r0 - btq0 * 196;
  const __bf16* a0 = X2p + (size_t)btq0 * 1204224 + (size_t)p0 * 512 + scol;
  const __bf16* b0 = Wtb + (size_t)(n0 + srow) * 512 + scol;
  const __bf16* b1 = Wtb + (size_t)(n0 + 64 + srow) * 512 + scol;
  char* sa0 = (char*)As + tid * 16;
  char* sb0 = (char*)Bs + tid * 16;
  char* sb1 = (char*)Bs + 4096 + tid * 16;

  int l = tid & 63, w = tid >> 6;
  int lm = l & 15, lq = l >> 4;
  int wm = w >> 1, wn = w & 1;

  ffrag4 acc[2][4] = {};
  for (int u = ug; u < ug + 3; ++u) {
    size_t au = (size_t)u * 100352;   // u * P * D
    size_t bu = (size_t)u * 262144;   // u * D * D
    for (int d0 = 0; d0 < 512; d0 += 32) {
      __syncthreads();
      async16(a0 + au + d0, sa0);
      async16(b0 + bu + d0, sb0);
      async16(b1 + bu + d0, sb1);
      __syncthreads();
      bfrag8 af[2], bfr[4];
#pragma unroll
      for (int i = 0; i < 2; ++i)
        af[i] = *(const bfrag8*)&As[(wm * 32 + i * 16 + lm) * 32 + lq * 8];
#pragma unroll
      for (int j = 0; j < 4; ++j)
        bfr[j] = *(const bfrag8*)&Bs[(wn * 64 + j * 16 + lm) * 32 + lq * 8];
#pragma unroll
      for (int i = 0; i < 2; ++i)
#pragma unroll
        for (int j = 0; j < 4; ++j)
          acc[i][j] = __builtin_amdgcn_mfma_f32_16x16x32_bf16(af[i], bfr[j], acc[i][j], 0, 0, 0);
    }
  }

#pragma unroll
  for (int i = 0; i < 2; ++i) {
    int mbase = m0 + wm * 32 + i * 16 + lq * 4;
#pragma unroll
    for (int j = 0; j < 4; ++j) {
      int n = n0 + wn * 64 + j * 16 + lm;
#pragma unroll
      for (int r = 0; r < 4; ++r) {
        int mr = mbase + r;
        atomicAdd(accb + (size_t)mr * 512 + n, acc[i][j][r]);
      }
    }
  }
}

// ------- tc epilogue + out-LN fused: xmid = x + gelu(acc/12 + sbt); x3b = LN(xmid)
__global__ __launch_bounds__(64) void tc_epi_norm_kernel(
    const float* __restrict__ accb, const float* __restrict__ x,
    const float* __restrict__ sbt,
    const float* __restrict__ alpha, const float* __restrict__ beta,
    float* __restrict__ xmid, __bf16* __restrict__ x3b)
{
  size_t row = blockIdx.x;
  int l = threadIdx.x;
  size_t base = row * 512 + l * 8;
  float4 c0 = *(const float4*)(accb + base);
  float4 c1 = *(const float4*)(accb + base + 4);
  float4 x0 = *(const float4*)(x + base);
  float4 x1 = *(const float4*)(x + base + 4);
  float4 s0 = *(const float4*)(sbt + l * 8);
  float4 s1 = *(const float4*)(sbt + l * 8 + 4);
  float cc[8] = {c0.x, c0.y, c0.z, c0.w, c1.x, c1.y, c1.z, c1.w};
  float xx[8] = {x0.x, x0.y, x0.z, x0.w, x1.x, x1.y, x1.z, x1.w};
  float sv[8] = {s0.x, s0.y, s0.z, s0.w, s1.x, s1.y, s1.z, s1.w};
  float f[8];
#pragma unroll
  for (int q = 0; q < 8; ++q)
    f[q] = xx[q] + gelu_exact(cc[q] * (1.f / 12.f) + sv[q]);
  *(float4*)(xmid + base)     = make_float4(f[0], f[1], f[2], f[3]);
  *(float4*)(xmid + base + 4) = make_float4(f[4], f[5], f[6], f[7]);
  float s = 0.f, ss = 0.f;
#pragma unroll
  for (int q = 0; q < 8; ++q) { s += f[q]; ss += f[q] * f[q]; }
#pragma unroll
  for (int off = 32; off; off >>= 1) { s += __shfl_xor(s, off); ss += __shfl_xor(ss, off); }
  float mu = s * (1.f / 512.f);
  float var = fmaxf((ss - 512.f * mu * mu) * (1.f / 511.f), 0.f);
  float inv = 1.f / (sqrtf(var) + EPS);
  const float* al = alpha + l * 8;
  const float* be = beta + l * 8;
  float4 a0 = *(const float4*)al, a1 = *(const float4*)(al + 4);
  float4 b0 = *(const float4*)be, b1 = *(const float4*)(be + 4);
  float aa[8] = {a0.x, a0.y, a0.z, a0.w, a1.x, a1.y, a1.z, a1.w};
  float bb[8] = {b0.x, b0.y, b0.z, b0.w, b1.x, b1.y, b1.z, b1.w};
  bfrag8 o;
#pragma unroll
  for (int q = 0; q < 8; ++q) o[q] = (__bf16)(aa[q] * (f[q] - mu) * inv + bb[q]);
  *(bfrag8*)(x3b + base) = o;
}

// ------------- MFMA attention v2: 32x32x16, S^T route, no-max softmax -------
__global__ __launch_bounds__(512, 4) void attn_kernel(
    const __bf16* __restrict__ Q, const __bf16* __restrict__ K,
    const __bf16* __restrict__ V, __bf16* __restrict__ av)
{
  __shared__ __bf16 Ks[196 * 64];
  __shared__ __bf16 Vt[64 * 208];
  __shared__ __bf16 Pball[8 * 32 * 20];

  int bid = blockIdx.x;
  int half = bid & 1;
  int h = (bid >> 1) & 7;
  int r0 = bid >> 4;               // 0..47
  int u = r0 % 12;
  int b = r0 / 12;

  const __bf16* Kp = K + ((size_t)(b * 12 + u) * 196) * 512 + h * 64;
  const __bf16* Vp = V + ((size_t)(b * 12 + u) * 196) * 512 + h * 64;

  for (int idx = threadIdx.x; idx < 196 * 8; idx += 512) {
    int r = idx >> 3, g = idx & 7;
    *(bfrag8*)&Ks[r * 64 + ((g ^ (r & 7)) * 8)] =
        *(const bfrag8*)&Kp[(size_t)r * 512 + g * 8];
  }
  for (int idx = threadIdx.x; idx < 64 * 6; idx += 512) {
    int r = idx / 6, c2 = 196 + (idx % 6) * 2;
    bf16p2 z; z.v[0] = (__bf16)0.f; z.v[1] = (__bf16)0.f;
    *(bf16p2*)&Vt[r * 208 + c2] = z;
  }
  for (int idx = threadIdx.x; idx < 98 * 8; idx += 512) {
    int r2 = (idx % 98) * 2, c8 = (idx / 98) * 8;
    bfrag8 va = *(const bfrag8*)&Vp[(size_t)r2 * 512 + c8];
    bfrag8 vb = *(const bfrag8*)&Vp[(size_t)(r2 + 1) * 512 + c8];
#pragma unroll
    for (int e = 0; e < 8; ++e) {
      bf16p2 pr; pr.v[0] = va[e]; pr.v[1] = vb[e];
      *(bf16p2*)&Vt[(c8 + e) * 208 + r2] = pr;
    }
  }
  __syncthreads();

  int w = threadIdx.x >> 6, l = threadIdx.x & 63;
  int l5 = l >> 5, c = l & 31;
  __bf16* Pb = Pball + w * (32 * 20);

  for (int unit = w; unit < 42; unit += 8) {
    int t = unit / 7, qt = unit - t * 7;
    int tq = half * 6 + t;
    const __bf16* Qp = Q + ((size_t)(b * 12 + tq) * 196) * 512 + h * 64;
    __bf16* avp = av + ((size_t)((b * 12 + tq) * 12 + u) * 196) * 512 + h * 64;
    int q0 = qt * 32;

    const __bf16* qp = Qp + (size_t)(q0 + c) * 512 + l5 * 8;
    bfrag8 qf[4];
    qf[0] = *(const bfrag8*)(qp);
    qf[1] = *(const bfrag8*)(qp + 16);
    qf[2] = *(const bfrag8*)(qp + 32);
    qf[3] = *(const bfrag8*)(qp + 48);

    ffrag16 O0, O1;
#pragma unroll
    for (int g = 0; g < 16; ++g) { O0[g] = 0.f; O1[g] = 0.f; }
    float sumacc = 0.f;

    for (int nt = 0; nt < 7; ++nt) {
      int key = nt * 32 + c; if (key > 195) key = 195;
      const __bf16* kbase = &Ks[key * 64];
      int kx = key & 7;

      ffrag16 s;
#pragma unroll
      for (int g = 0; g < 16; ++g) s[g] = 0.f;
#pragma unroll
      for (int kc = 0; kc < 4; ++kc) {
        bfrag8 kf = *(const bfrag8*)&kbase[(((kc * 2 + l5) ^ kx) * 8)];
        s = __builtin_amdgcn_mfma_f32_32x32x16_bf16(kf, qf[kc], s, 0, 0, 0);
      }

#pragma unroll
      for (int g = 0; g < 16; ++g) {
        float e = __expf(s[g] * 0.125f);
        bool keep = (nt < 6) || ((g < 4) && (l5 == 0));
        e = keep ? e : 0.f;
        s[g] = e;
        sumacc += e;
      }

#pragma unroll
      for (int sub = 0; sub < 2; ++sub) {
        if (nt == 6 && sub == 1) break;
#pragma unroll
        for (int g = 0; g < 8; ++g) {
          int gg = sub * 8 + g;
          int k16 = (gg & 3) + 8 * ((gg >> 2) & 1) + 4 * l5;
          Pb[c * 20 + k16] = (__bf16)s[gg];
        }
        __threadfence_block();
        int ch = nt * 2 + sub;
        bfrag4 plo = *(const bfrag4*)&Pb[c * 20 + l5 * 8];
        bfrag4 phi = *(const bfrag4*)&Pb[c * 20 + l5 * 8 + 4];
        bfrag8 pa = __builtin_shufflevector(plo, phi, 0, 1, 2, 3, 4, 5, 6, 7);
        bfrag8 v0 = *(const bfrag8*)&Vt[(size_t)(c     ) * 208 + ch * 16 + l5 * 8];
        bfrag8 v1 = *(const bfrag8*)&Vt[(size_t)(c + 32) * 208 + ch * 16 + l5 * 8];
        O0 = __builtin_amdgcn_mfma_f32_32x32x16_bf16(pa, v0, O0, 0, 0, 0);
        O1 = __builtin_amdgcn_mfma_f32_32x32x16_bf16(pa, v1, O1, 0, 0, 0);
      }
    }

    float stot = sumacc + __shfl_xor(sumacc, 32);

#pragma unroll
    for (int g = 0; g < 16; ++g) {
      int row = (g & 3) + 8 * (g >> 2) + 4 * l5;
      float sq = __shfl(stot, row);
      float iv = __builtin_amdgcn_rcpf(sq);
      int q = q0 + row;
      if (q < 196) {
        size_t base = (size_t)q * 512 + c;
        avp[base]      = (__bf16)(O0[g] * iv);
        avp[base + 32] = (__bf16)(O1[g] * iv);
      }
    }
  }
}

extern "C" void kernel_launch(void* const* d_in, const int* in_sizes, int n_in,
                              void* d_out, int out_size, void* d_ws, size_t ws_size,
                              hipStream_t stream)
{
  const float* x      = (const float*)d_in[0];
  const float* Wq     = (const float*)d_in[1];
  const float* bq     = (const float*)d_in[2];
  const float* Wk     = (const float*)d_in[3];
  const float* bk     = (const float*)d_in[4];
  const float* Wv     = (const float*)d_in[5];
  const float* bv     = (const float*)d_in[6];
  const float* in_a   = (const float*)d_in[7];
  const float* in_b   = (const float*)d_in[8];
  const float* attn_a = (const float*)d_in[9];
  const float* attn_b = (const float*)d_in[10];
  const float* out_a  = (const float*)d_in[11];
  const float* out_b  = (const float*)d_in[12];
  const float* Wt     = (const float*)d_in[13];
  const float* bt     = (const float*)d_in[14];
  const float* pos    = (const float*)d_in[15];
  const float* W1     = (const float*)d_in[16];
  const float* b1     = (const float*)d_in[17];
  const float* W2     = (const float*)d_in[18];
  const float* b2     = (const float*)d_in[19];

  char* ws = (char*)d_ws;
  const size_t bfb = (size_t)9408 * 512 * 2;       // 9,633,792 B (bf16 MxD)
  __bf16* x2b  = (__bf16*)(ws);
  __bf16* Qb   = (__bf16*)(ws + bfb);
  __bf16* Kb   = (__bf16*)(ws + 2 * bfb);
  __bf16* Vb   = (__bf16*)(ws + 3 * bfb);
  __bf16* av   = (__bf16*)(ws + 4 * bfb);          // 115,605,504 B
  char*   wreg = ws + 4 * bfb + (size_t)115605504; // weights bf16, 9,961,472 B
  __bf16* Wqb  = (__bf16*)(wreg);
  __bf16* Wkb  = (__bf16*)(wreg) + 262144;
  __bf16* Wvb  = (__bf16*)(wreg) + 524288;
  __bf16* W1b  = (__bf16*)(wreg) + 786432;
  __bf16* W2b  = (__bf16*)(wreg) + 1310720;
  __bf16* Wtb  = (__bf16*)(wreg) + 1835008;
  float*  sbt  = (float*)(wreg + 9961472);
  float*  accb = (float*)(wreg + 9963520);         // 19,267,584 B split-K acc
  // overlays (stream-ordered lifetimes):
  float*  xmid = (float*)(ws);                     // over x2b+Qb
  __bf16* x3b  = (__bf16*)(ws + 2 * bfb);          // over Kb
  __bf16* hb   = (__bf16*)(ws + 4 * bfb);          // over av
  float*  out  = (float*)d_out;

  conv_w_kernel<<<2432, 256, 0, stream>>>(Wq, Wk, Wv, W1, W2, Wt, (__bf16*)wreg);
  sum_bt_kernel<<<1, 512, 0, stream>>>(bt, sbt);
  zero_acc_kernel<<<4704, 256, 0, stream>>>(accb);
  norm_f32_to_bf16_kernel<<<9408, 64, 0, stream>>>(x, x2b, in_a, in_b);
  mfma_nt_kernel<<<dim3(12, 147), 256, 0, stream>>>(
      x2b, Wqb, Wkb, Wvb, bq, bk, bv, Qb, Kb, Vb, nullptr, nullptr, 512, 0);
  attn_kernel<<<768, 512, 0, stream>>>(Qb, Kb, Vb, av);
  norm_av_kernel<<<112896, 64, 0, stream>>>((bf16*)av, attn_a, attn_b, pos);
  mfma_tc_kernel<<<dim3(4, 147, 4), 256, 0, stream>>>(av, Wtb, accb);
  tc_epi_norm_kernel<<<9408, 64, 0, stream>>>(accb, x, sbt, out_a, out_b, xmid, x3b);
  mfma_nt_kernel<<<dim3(8, 147), 256, 0, stream>>>(
      x3b, W1b, nullptr, nullptr, b1, nullptr, nullptr, hb, nullptr, nullptr,
      nullptr, nullptr, 512, 1);
  mfma_nt_kernel<<<dim3(4, 147), 256, 0, stream>>>(
      hb, W2b, nullptr, nullptr, b2, nullptr, nullptr, nullptr, nullptr, nullptr,
      xmid, out, 1024, 2);
}